// Round 3
// baseline (801.013 us; speedup 1.0000x reference)
//
#include <hip/hip_runtime.h>

// ---------------------------------------------------------------------------
// GIN forward (eval mode), fp32 baseline.
// Structure: fold BN into weights once per call; embed; build CSR (in-edges
// per node); per layer: GEMM(relu) -> aggregate -> GEMM(relu) -> GEMM;
// readout dot + segment-sum over sorted batch via atomics.
// ---------------------------------------------------------------------------

#define HD 128          // hidden channels
#define NLAYER 3

// ---------------- prep: fold batchnorms into weights ----------------
__global__ void prep_weights(
    const float* __restrict__ bn_g, const float* __restrict__ bn_b,
    const float* __restrict__ bn_m, const float* __restrict__ bn_v,
    const float* __restrict__ lin_w, const float* __restrict__ lin_b,
    const float* __restrict__ mbn_g, const float* __restrict__ mbn_b,
    const float* __restrict__ mbn_m, const float* __restrict__ mbn_v,
    const float* __restrict__ mlp_w1, const float* __restrict__ mlp_b1,
    float* __restrict__ fwlin, float* __restrict__ fblin,
    float* __restrict__ fw1,   float* __restrict__ fb1)
{
    const int l = blockIdx.x;      // layer
    const int j = threadIdx.x;     // 128 threads = one output column each
    __shared__ float sa[HD], sc[HD];

    const int lb = l * HD;
    float a = bn_g[lb + j] * rsqrtf(bn_v[lb + j] + 1e-5f);
    float c = bn_b[lb + j] - bn_m[lb + j] * a;
    sa[j] = a; sc[j] = c;
    __syncthreads();

    // pre-BN fold: bn(h)@W + b  ==  h @ (a_k * W[k][j]) + (b[j] + sum_k c_k W[k][j])
    float accb = lin_b[lb + j];
    const int wb = l * HD * HD;
    for (int k = 0; k < HD; ++k) {
        float w = lin_w[wb + k * HD + j];
        fwlin[wb + k * HD + j] = sa[k] * w;
        accb += sc[k] * w;
    }
    fblin[lb + j] = accb;

    // post-BN fold: bn(h@W1 + b1) == h @ (a2_j W1[k][j]) + (a2_j b1[j] + c2_j)
    float a2 = mbn_g[lb + j] * rsqrtf(mbn_v[lb + j] + 1e-5f);
    float c2 = mbn_b[lb + j] - mbn_m[lb + j] * a2;
    for (int k = 0; k < HD; ++k) {
        fw1[wb + k * HD + j] = a2 * mlp_w1[wb + k * HD + j];
    }
    fb1[lb + j] = a2 * mlp_b1[lb + j] + c2;
}

// ---------------- embedding gather ----------------
__global__ void embed_kernel(const int* __restrict__ x,
                             const float* __restrict__ table,
                             float* __restrict__ h, int n)
{
    int gid = blockIdx.x * blockDim.x + threadIdx.x;
    if (gid >= n * 32) return;
    int node = gid >> 5, c4 = gid & 31;
    int id = x[node];
    reinterpret_cast<float4*>(h)[(size_t)node * 32 + c4] =
        reinterpret_cast<const float4*>(table)[(size_t)id * 32 + c4];
}

// ---------------- CSR build ----------------
__global__ void count_deg(const int* __restrict__ dst, int* __restrict__ deg, int e)
{
    int i = blockIdx.x * blockDim.x + threadIdx.x;
    if (i < e) atomicAdd(&deg[dst[i]], 1);
}

// block scans 1024 elements (256 threads x 4)
__global__ void scan_blocks(const int* __restrict__ deg, int* __restrict__ excl,
                            int* __restrict__ partials, int n)
{
    __shared__ int wt[4];
    int t = threadIdx.x;
    int base = blockIdx.x * 1024 + t * 4;
    int v0 = (base + 0 < n) ? deg[base + 0] : 0;
    int v1 = (base + 1 < n) ? deg[base + 1] : 0;
    int v2 = (base + 2 < n) ? deg[base + 2] : 0;
    int v3 = (base + 3 < n) ? deg[base + 3] : 0;
    int s = v0 + v1 + v2 + v3;
    int lane = t & 63, w = t >> 6;
    int inc = s;
    #pragma unroll
    for (int d = 1; d < 64; d <<= 1) {
        int o = __shfl_up(inc, d);
        if (lane >= d) inc += o;
    }
    if (lane == 63) wt[w] = inc;
    __syncthreads();
    int off = 0;
    for (int i = 0; i < w; ++i) off += wt[i];
    int ex = off + inc - s;   // exclusive prefix of this thread's 4 elements
    if (base + 0 < n) excl[base + 0] = ex; ex += v0;
    if (base + 1 < n) excl[base + 1] = ex; ex += v1;
    if (base + 2 < n) excl[base + 2] = ex; ex += v2;
    if (base + 3 < n) excl[base + 3] = ex;
    if (t == 255) partials[blockIdx.x] = off + inc;
}

__global__ void scan_small(int* __restrict__ partials, int nb)
{
    int t = threadIdx.x;   // 64 threads, nb <= 64
    int v = (t < nb) ? partials[t] : 0;
    int inc = v;
    #pragma unroll
    for (int d = 1; d < 64; d <<= 1) {
        int o = __shfl_up(inc, d);
        if (t >= d) inc += o;
    }
    if (t < nb) partials[t] = inc - v;   // exclusive
}

__global__ void scan_add(int* __restrict__ rowst, int* __restrict__ cursor,
                         const int* __restrict__ partials, int n, int e)
{
    int idx = blockIdx.x * blockDim.x + threadIdx.x;
    if (idx < n) {
        int v = rowst[idx] + partials[idx >> 10];
        rowst[idx] = v;
        cursor[idx] = v;
    }
    if (idx == 0) rowst[n] = e;
}

__global__ void fill_csr(const int* __restrict__ src, const int* __restrict__ dst,
                         int* __restrict__ cursor, int* __restrict__ esrc, int e)
{
    int i = blockIdx.x * blockDim.x + threadIdx.x;
    if (i < e) {
        int p = atomicAdd(&cursor[dst[i]], 1);
        esrc[p] = src[i];
    }
}

// ---------------- GEMM: Y = act(X @ W + B), X:[n,128] W:[128,128] ----------------
// Block: 256 threads = 4 waves. Tile: 64 rows. Wave w owns cols [32w,32w+32).
// X tile staged in LDS (stride 129 -> 2-way bank alias = free).
// W rows fetched as wave-uniform scalar loads (SMEM pipe), feed v_fmac SGPR src.
template<bool RELU>
__global__ __launch_bounds__(256, 4)
void gemm128(const float* __restrict__ X, const float* __restrict__ W,
             const float* __restrict__ B, float* __restrict__ Y, int n)
{
    __shared__ float sH[64 * 129];
    const int t = threadIdx.x;
    const int lane = t & 63;
    const int cbase = __builtin_amdgcn_readfirstlane((t >> 6) << 5);
    const int tile = blockIdx.x * 64;

    // stage 64x128 X tile (coalesced float4 loads, scalar LDS stores)
    for (int i = t; i < 64 * 32; i += 256) {
        int row = i >> 5, k4 = i & 31;
        float4 v = make_float4(0.f, 0.f, 0.f, 0.f);
        if (tile + row < n)
            v = reinterpret_cast<const float4*>(X)[(size_t)(tile + row) * 32 + k4];
        float* d = &sH[row * 129 + k4 * 4];
        d[0] = v.x; d[1] = v.y; d[2] = v.z; d[3] = v.w;
    }
    __syncthreads();

    float acc[32];
    #pragma unroll
    for (int j = 0; j < 32; ++j) acc[j] = 0.f;

    const float* Wc = W + cbase;
    for (int k = 0; k < HD; ++k) {
        float hv = sH[lane * 129 + k];
        const float* wr = Wc + k * HD;       // uniform -> s_load
        #pragma unroll
        for (int j = 0; j < 32; ++j) acc[j] = fmaf(hv, wr[j], acc[j]);
    }

    int row = tile + lane;
    if (row < n) {
        float* yr = Y + (size_t)row * HD + cbase;
        #pragma unroll
        for (int j = 0; j < 32; ++j) {
            float v = acc[j] + B[cbase + j];
            if (RELU) v = fmaxf(v, 0.f);
            yr[j] = v;
        }
    }
}

// ---------------- aggregation: z[n] = (1+eps)*h2[n] + sum_{in-edges} h2[src] ----
__global__ void aggregate(const float* __restrict__ h2, const int* __restrict__ rowst,
                          const int* __restrict__ esrc, const float* __restrict__ epsp,
                          int layer, float* __restrict__ z, int n)
{
    int gw = (blockIdx.x * blockDim.x + threadIdx.x) >> 6;   // one wave per node
    int lane = threadIdx.x & 63;
    if (gw >= n) return;
    float se = 1.0f + epsp[layer];
    int rs = __builtin_amdgcn_readfirstlane(rowst[gw]);
    int re = __builtin_amdgcn_readfirstlane(rowst[gw + 1]);
    const float2* h2v = reinterpret_cast<const float2*>(h2);
    float2 a = h2v[(size_t)gw * 64 + lane];
    float accx = se * a.x, accy = se * a.y;
    for (int e = rs; e < re; ++e) {
        int s = esrc[e];                     // uniform scalar load
        float2 v = h2v[(size_t)s * 64 + lane];
        accx += v.x; accy += v.y;
    }
    float2 o; o.x = accx; o.y = accy;
    reinterpret_cast<float2*>(z)[(size_t)gw * 64 + lane] = o;
}

// ---------------- readout: out[batch[n]] += h[n].ro_w + ro_b ----------------
__global__ void readout(const float* __restrict__ h, const float* __restrict__ rw,
                        const float* __restrict__ rb, const int* __restrict__ batch,
                        float* __restrict__ out, int n)
{
    int gw = (blockIdx.x * blockDim.x + threadIdx.x) >> 6;
    int lane = threadIdx.x & 63;
    if (gw >= n) return;
    float2 hv = reinterpret_cast<const float2*>(h)[(size_t)gw * 64 + lane];
    float2 wv = reinterpret_cast<const float2*>(rw)[lane];
    float p = hv.x * wv.x + hv.y * wv.y;
    #pragma unroll
    for (int d = 32; d; d >>= 1) p += __shfl_xor(p, d);
    if (lane == 0) atomicAdd(&out[batch[gw]], p + rb[0]);
}

// ---------------------------------------------------------------------------
extern "C" void kernel_launch(void* const* d_in, const int* in_sizes, int n_in,
                              void* d_out, int out_size, void* d_ws, size_t ws_size,
                              hipStream_t stream)
{
    const int N = in_sizes[0];          // 50000
    const int E = in_sizes[1] / 2;      // 800000
    const int G = out_size;             // 512

    const int*   x      = (const int*)d_in[0];
    const int*   ei     = (const int*)d_in[1];
    const int*   batch  = (const int*)d_in[2];
    const float* table  = (const float*)d_in[3];
    const float* bn_g   = (const float*)d_in[4];
    const float* bn_b   = (const float*)d_in[5];
    const float* bn_m   = (const float*)d_in[6];
    const float* bn_v   = (const float*)d_in[7];
    const float* lin_w  = (const float*)d_in[8];
    const float* lin_b  = (const float*)d_in[9];
    const float* epsv   = (const float*)d_in[10];
    const float* mlp_w1 = (const float*)d_in[11];
    const float* mlp_b1 = (const float*)d_in[12];
    const float* mbn_g  = (const float*)d_in[13];
    const float* mbn_b  = (const float*)d_in[14];
    const float* mbn_m  = (const float*)d_in[15];
    const float* mbn_v  = (const float*)d_in[16];
    const float* mlp_w2 = (const float*)d_in[17];
    const float* mlp_b2 = (const float*)d_in[18];
    const float* ro_w   = (const float*)d_in[19];
    const float* ro_b   = (const float*)d_in[20];

    const int* esrc_in = ei;        // edge_index[0]
    const int* edst_in = ei + E;    // edge_index[1]

    // ---- workspace carve-up (all offsets 256B aligned) ----
    char* w = (char*)d_ws;
    size_t off = 0;
    auto alloc = [&](size_t bytes) {
        void* p = w + off;
        off += (bytes + 255) & ~(size_t)255;
        return p;
    };
    float* buf0   = (float*)alloc((size_t)N * HD * 4);
    float* buf1   = (float*)alloc((size_t)N * HD * 4);
    float* fwlin  = (float*)alloc((size_t)NLAYER * HD * HD * 4);
    float* fblin  = (float*)alloc((size_t)NLAYER * HD * 4);
    float* fw1    = (float*)alloc((size_t)NLAYER * HD * HD * 4);
    float* fb1    = (float*)alloc((size_t)NLAYER * HD * 4);
    int*   deg    = (int*)alloc((size_t)N * 4);
    int*   rowst  = (int*)alloc((size_t)(N + 1) * 4);
    int*   cursor = (int*)alloc((size_t)N * 4);
    int*   esrc   = (int*)alloc((size_t)E * 4);
    int*   part   = (int*)alloc(256 * 4);
    (void)ws_size;

    hipMemsetAsync(deg, 0, (size_t)N * 4, stream);
    hipMemsetAsync(d_out, 0, (size_t)G * 4, stream);

    prep_weights<<<NLAYER, HD, 0, stream>>>(bn_g, bn_b, bn_m, bn_v, lin_w, lin_b,
                                            mbn_g, mbn_b, mbn_m, mbn_v, mlp_w1, mlp_b1,
                                            fwlin, fblin, fw1, fb1);
    embed_kernel<<<(N * 32 + 255) / 256, 256, 0, stream>>>(x, table, buf0, N);

    count_deg<<<(E + 255) / 256, 256, 0, stream>>>(edst_in, deg, E);
    int nb = (N + 1023) / 1024;
    scan_blocks<<<nb, 256, 0, stream>>>(deg, rowst, part, N);
    scan_small<<<1, 64, 0, stream>>>(part, nb);
    scan_add<<<(N + 255) / 256, 256, 0, stream>>>(rowst, cursor, part, N, E);
    fill_csr<<<(E + 255) / 256, 256, 0, stream>>>(esrc_in, edst_in, cursor, esrc, E);

    const int gemm_grid = (N + 63) / 64;
    const int wave_grid = (N + 3) / 4;   // 4 waves per 256-thread block

    for (int l = 0; l < NLAYER; ++l) {
        // h2 = relu(bn(h) @ lin_w + lin_b)   [folded]
        gemm128<true><<<gemm_grid, 256, 0, stream>>>(
            buf0, fwlin + (size_t)l * HD * HD, fblin + (size_t)l * HD, buf1, N);
        // z = (1+eps)*h2 + gather-sum
        aggregate<<<wave_grid, 256, 0, stream>>>(buf1, rowst, esrc, epsv, l, buf0, N);
        // z2 = relu(bn(z @ mlp_w1 + b1))     [folded]
        gemm128<true><<<gemm_grid, 256, 0, stream>>>(
            buf0, fw1 + (size_t)l * HD * HD, fb1 + (size_t)l * HD, buf1, N);
        // h = z2 @ mlp_w2 + b2
        gemm128<false><<<gemm_grid, 256, 0, stream>>>(
            buf1, mlp_w2 + (size_t)l * HD * HD, mlp_b2 + (size_t)l * HD, buf0, N);
    }

    readout<<<wave_grid, 256, 0, stream>>>(buf0, ro_w, ro_b, batch, (float*)d_out, N);
}

// Round 4
// 672.955 us; speedup vs baseline: 1.1903x; 1.1903x over previous
//
#include <hip/hip_runtime.h>

// ---------------------------------------------------------------------------
// GIN forward (eval mode), fp32.
// Round-4 structure: fold BN into weights; CSR build; per layer:
//   GEMM(relu, gather-staged from embed table on layer 0) -> aggregate ->
//   GEMM(relu) -> GEMM (last layer: fused readout-dot + segmented-scan
//   graph reduction, no h write).
// ---------------------------------------------------------------------------

#define HD 128          // hidden channels
#define NLAYER 3

// ---------------- prep: fold batchnorms into weights ----------------
__global__ void prep_weights(
    const float* __restrict__ bn_g, const float* __restrict__ bn_b,
    const float* __restrict__ bn_m, const float* __restrict__ bn_v,
    const float* __restrict__ lin_w, const float* __restrict__ lin_b,
    const float* __restrict__ mbn_g, const float* __restrict__ mbn_b,
    const float* __restrict__ mbn_m, const float* __restrict__ mbn_v,
    const float* __restrict__ mlp_w1, const float* __restrict__ mlp_b1,
    float* __restrict__ fwlin, float* __restrict__ fblin,
    float* __restrict__ fw1,   float* __restrict__ fb1)
{
    const int l = blockIdx.x;      // layer
    const int j = threadIdx.x;     // 128 threads = one output column each
    __shared__ float sa[HD], sc[HD];

    const int lb = l * HD;
    float a = bn_g[lb + j] * rsqrtf(bn_v[lb + j] + 1e-5f);
    float c = bn_b[lb + j] - bn_m[lb + j] * a;
    sa[j] = a; sc[j] = c;
    __syncthreads();

    // pre-BN fold: bn(h)@W + b  ==  h @ (a_k * W[k][j]) + (b[j] + sum_k c_k W[k][j])
    float accb = lin_b[lb + j];
    const int wb = l * HD * HD;
    for (int k = 0; k < HD; ++k) {
        float w = lin_w[wb + k * HD + j];
        fwlin[wb + k * HD + j] = sa[k] * w;
        accb += sc[k] * w;
    }
    fblin[lb + j] = accb;

    // post-BN fold: bn(h@W1 + b1) == h @ (a2_j W1[k][j]) + (a2_j b1[j] + c2_j)
    float a2 = mbn_g[lb + j] * rsqrtf(mbn_v[lb + j] + 1e-5f);
    float c2 = mbn_b[lb + j] - mbn_m[lb + j] * a2;
    for (int k = 0; k < HD; ++k) {
        fw1[wb + k * HD + j] = a2 * mlp_w1[wb + k * HD + j];
    }
    fb1[lb + j] = a2 * mlp_b1[lb + j] + c2;
}

// ---------------- CSR build ----------------
__global__ void count_deg(const int* __restrict__ dst, int* __restrict__ deg, int e)
{
    int i = blockIdx.x * blockDim.x + threadIdx.x;
    if (i < e) atomicAdd(&deg[dst[i]], 1);
}

// block scans 1024 elements (256 threads x 4)
__global__ void scan_blocks(const int* __restrict__ deg, int* __restrict__ excl,
                            int* __restrict__ partials, int n)
{
    __shared__ int wt[4];
    int t = threadIdx.x;
    int base = blockIdx.x * 1024 + t * 4;
    int v0 = (base + 0 < n) ? deg[base + 0] : 0;
    int v1 = (base + 1 < n) ? deg[base + 1] : 0;
    int v2 = (base + 2 < n) ? deg[base + 2] : 0;
    int v3 = (base + 3 < n) ? deg[base + 3] : 0;
    int s = v0 + v1 + v2 + v3;
    int lane = t & 63, w = t >> 6;
    int inc = s;
    #pragma unroll
    for (int d = 1; d < 64; d <<= 1) {
        int o = __shfl_up(inc, d);
        if (lane >= d) inc += o;
    }
    if (lane == 63) wt[w] = inc;
    __syncthreads();
    int off = 0;
    for (int i = 0; i < w; ++i) off += wt[i];
    int ex = off + inc - s;   // exclusive prefix of this thread's 4 elements
    if (base + 0 < n) excl[base + 0] = ex; ex += v0;
    if (base + 1 < n) excl[base + 1] = ex; ex += v1;
    if (base + 2 < n) excl[base + 2] = ex; ex += v2;
    if (base + 3 < n) excl[base + 3] = ex;
    if (t == 255) partials[blockIdx.x] = off + inc;
}

__global__ void scan_small(int* __restrict__ partials, int nb)
{
    int t = threadIdx.x;   // 64 threads, nb <= 64
    int v = (t < nb) ? partials[t] : 0;
    int inc = v;
    #pragma unroll
    for (int d = 1; d < 64; d <<= 1) {
        int o = __shfl_up(inc, d);
        if (t >= d) inc += o;
    }
    if (t < nb) partials[t] = inc - v;   // exclusive
}

__global__ void scan_add(int* __restrict__ rowst, int* __restrict__ cursor,
                         const int* __restrict__ partials, int n, int e)
{
    int idx = blockIdx.x * blockDim.x + threadIdx.x;
    if (idx < n) {
        int v = rowst[idx] + partials[idx >> 10];
        rowst[idx] = v;
        cursor[idx] = v;
    }
    if (idx == 0) rowst[n] = e;
}

__global__ void fill_csr(const int* __restrict__ src, const int* __restrict__ dst,
                         int* __restrict__ cursor, int* __restrict__ esrc, int e)
{
    int i = blockIdx.x * blockDim.x + threadIdx.x;
    if (i < e) {
        int p = atomicAdd(&cursor[dst[i]], 1);
        esrc[p] = src[i];
    }
}

// ---------------- GEMM: Y = act(X @ W + B), X:[n,128] W:[128,128] ----------------
// Block: 256 threads = 4 waves. Tile: 64 rows. Wave w owns cols [32w,32w+32).
// X tile staged in LDS (stride 129 -> 2-way bank alias = free).
// GATHER: stage rows from X[xidx[row]] (fused embedding on layer 0).
// FUSE:   no Y write; per-row dot with rw, cross-wave LDS reduce, then
//         wave-segmented scan over sorted batch -> few atomics into gout.
template<bool GATHER, bool RELU, bool FUSE>
__global__ __launch_bounds__(256, 4)
void gemm128(const float* __restrict__ X, const int* __restrict__ xidx,
             const float* __restrict__ W, const float* __restrict__ B,
             float* __restrict__ Y,
             const float* __restrict__ rw, const float* __restrict__ rb,
             const int* __restrict__ batch, float* __restrict__ gout,
             int n)
{
    __shared__ float sH[64 * 129];
    __shared__ float sD[64][4];
    const int t = threadIdx.x;
    const int lane = t & 63;
    const int wv = t >> 6;
    const int cbase = __builtin_amdgcn_readfirstlane(wv << 5);
    const int tile = blockIdx.x * 64;

    // stage 64x128 X tile (coalesced float4 loads, scalar LDS stores)
    for (int i = t; i < 64 * 32; i += 256) {
        int row = i >> 5, k4 = i & 31;
        float4 v = make_float4(0.f, 0.f, 0.f, 0.f);
        if (tile + row < n) {
            size_t r = GATHER ? (size_t)xidx[tile + row] : (size_t)(tile + row);
            v = reinterpret_cast<const float4*>(X)[r * 32 + k4];
        }
        float* d = &sH[row * 129 + k4 * 4];
        d[0] = v.x; d[1] = v.y; d[2] = v.z; d[3] = v.w;
    }
    __syncthreads();

    float acc[32];
    #pragma unroll
    for (int j = 0; j < 32; ++j) acc[j] = 0.f;

    const float* Wc = W + cbase;
    for (int k = 0; k < HD; ++k) {
        float hv = sH[lane * 129 + k];
        const float* wr = Wc + k * HD;       // uniform -> s_load
        #pragma unroll
        for (int j = 0; j < 32; ++j) acc[j] = fmaf(hv, wr[j], acc[j]);
    }

    if (!FUSE) {
        int row = tile + lane;
        if (row < n) {
            float* yr = Y + (size_t)row * HD + cbase;
            #pragma unroll
            for (int j = 0; j < 32; ++j) {
                float v = acc[j] + B[cbase + j];
                if (RELU) v = fmaxf(v, 0.f);
                yr[j] = v;
            }
        }
    } else {
        // per-row partial dot over this wave's 32-col slice
        float part = 0.f;
        #pragma unroll
        for (int j = 0; j < 32; ++j)
            part = fmaf(acc[j] + B[cbase + j], rw[cbase + j], part);
        sD[lane][wv] = part;
        __syncthreads();
        if (t < 64) {                         // wave 0 flushes 64 rows
            int row = tile + t;
            float v = sD[t][0] + sD[t][1] + sD[t][2] + sD[t][3] + rb[0];
            int b = (row < n) ? batch[row] : -1;
            if (row >= n) v = 0.f;
            // segmented inclusive scan over sorted batch ids
            #pragma unroll
            for (int d = 1; d < 64; d <<= 1) {
                int   ob = __shfl_up(b, d);
                float ov = __shfl_up(v, d);
                if (t >= d && ob == b) v += ov;
            }
            int nb2 = __shfl_down(b, 1);
            bool lastl = (t == 63) || (nb2 != b);
            if (lastl && b >= 0) atomicAdd(&gout[b], v);
        }
    }
}

// ---------------- aggregation: z[n] = (1+eps)*h2[n] + sum_{in-edges} h2[src] ----
// Lane-parallel edge-id loads broadcast via shfl; 4 independent accumulators
// keep 4 gathers in flight.
__global__ void aggregate(const float* __restrict__ h2, const int* __restrict__ rowst,
                          const int* __restrict__ esrc, const float* __restrict__ epsp,
                          int layer, float* __restrict__ z, int n)
{
    int gw = (blockIdx.x * blockDim.x + threadIdx.x) >> 6;   // one wave per node
    int lane = threadIdx.x & 63;
    if (gw >= n) return;
    float se = 1.0f + epsp[layer];
    int rs = __builtin_amdgcn_readfirstlane(rowst[gw]);
    int re = __builtin_amdgcn_readfirstlane(rowst[gw + 1]);
    const float2* h2v = reinterpret_cast<const float2*>(h2);
    float2 a = h2v[(size_t)gw * 64 + lane];
    float ax0 = se * a.x, ay0 = se * a.y;
    float ax1 = 0.f, ay1 = 0.f, ax2 = 0.f, ay2 = 0.f, ax3 = 0.f, ay3 = 0.f;
    for (int base = rs; base < re; base += 64) {
        int cnt = re - base; if (cnt > 64) cnt = 64;
        int eid = (base + lane < re) ? esrc[base + lane] : 0;
        int j = 0;
        for (; j + 4 <= cnt; j += 4) {
            int s0 = __shfl(eid, j + 0);
            int s1 = __shfl(eid, j + 1);
            int s2 = __shfl(eid, j + 2);
            int s3 = __shfl(eid, j + 3);
            float2 v0 = h2v[(size_t)s0 * 64 + lane];
            float2 v1 = h2v[(size_t)s1 * 64 + lane];
            float2 v2 = h2v[(size_t)s2 * 64 + lane];
            float2 v3 = h2v[(size_t)s3 * 64 + lane];
            ax0 += v0.x; ay0 += v0.y;
            ax1 += v1.x; ay1 += v1.y;
            ax2 += v2.x; ay2 += v2.y;
            ax3 += v3.x; ay3 += v3.y;
        }
        for (; j < cnt; ++j) {
            int s0 = __shfl(eid, j);
            float2 v0 = h2v[(size_t)s0 * 64 + lane];
            ax0 += v0.x; ay0 += v0.y;
        }
    }
    float2 o;
    o.x = (ax0 + ax1) + (ax2 + ax3);
    o.y = (ay0 + ay1) + (ay2 + ay3);
    reinterpret_cast<float2*>(z)[(size_t)gw * 64 + lane] = o;
}

// ---------------------------------------------------------------------------
extern "C" void kernel_launch(void* const* d_in, const int* in_sizes, int n_in,
                              void* d_out, int out_size, void* d_ws, size_t ws_size,
                              hipStream_t stream)
{
    const int N = in_sizes[0];          // 50000
    const int E = in_sizes[1] / 2;      // 800000
    const int G = out_size;             // 512

    const int*   x      = (const int*)d_in[0];
    const int*   ei     = (const int*)d_in[1];
    const int*   batch  = (const int*)d_in[2];
    const float* table  = (const float*)d_in[3];
    const float* bn_g   = (const float*)d_in[4];
    const float* bn_b   = (const float*)d_in[5];
    const float* bn_m   = (const float*)d_in[6];
    const float* bn_v   = (const float*)d_in[7];
    const float* lin_w  = (const float*)d_in[8];
    const float* lin_b  = (const float*)d_in[9];
    const float* epsv   = (const float*)d_in[10];
    const float* mlp_w1 = (const float*)d_in[11];
    const float* mlp_b1 = (const float*)d_in[12];
    const float* mbn_g  = (const float*)d_in[13];
    const float* mbn_b  = (const float*)d_in[14];
    const float* mbn_m  = (const float*)d_in[15];
    const float* mbn_v  = (const float*)d_in[16];
    const float* mlp_w2 = (const float*)d_in[17];
    const float* mlp_b2 = (const float*)d_in[18];
    const float* ro_w   = (const float*)d_in[19];
    const float* ro_b   = (const float*)d_in[20];

    const int* esrc_in = ei;        // edge_index[0]
    const int* edst_in = ei + E;    // edge_index[1]

    // ---- workspace carve-up (all offsets 256B aligned) ----
    char* w = (char*)d_ws;
    size_t off = 0;
    auto alloc = [&](size_t bytes) {
        void* p = w + off;
        off += (bytes + 255) & ~(size_t)255;
        return p;
    };
    float* buf0   = (float*)alloc((size_t)N * HD * 4);
    float* buf1   = (float*)alloc((size_t)N * HD * 4);
    float* fwlin  = (float*)alloc((size_t)NLAYER * HD * HD * 4);
    float* fblin  = (float*)alloc((size_t)NLAYER * HD * 4);
    float* fw1    = (float*)alloc((size_t)NLAYER * HD * HD * 4);
    float* fb1    = (float*)alloc((size_t)NLAYER * HD * 4);
    int*   deg    = (int*)alloc((size_t)N * 4);
    int*   rowst  = (int*)alloc((size_t)(N + 1) * 4);
    int*   cursor = (int*)alloc((size_t)N * 4);
    int*   esrc   = (int*)alloc((size_t)E * 4);
    int*   part   = (int*)alloc(256 * 4);
    (void)ws_size;

    hipMemsetAsync(deg, 0, (size_t)N * 4, stream);
    hipMemsetAsync(d_out, 0, (size_t)G * 4, stream);

    prep_weights<<<NLAYER, HD, 0, stream>>>(bn_g, bn_b, bn_m, bn_v, lin_w, lin_b,
                                            mbn_g, mbn_b, mbn_m, mbn_v, mlp_w1, mlp_b1,
                                            fwlin, fblin, fw1, fb1);

    count_deg<<<(E + 255) / 256, 256, 0, stream>>>(edst_in, deg, E);
    int nb = (N + 1023) / 1024;
    scan_blocks<<<nb, 256, 0, stream>>>(deg, rowst, part, N);
    scan_small<<<1, 64, 0, stream>>>(part, nb);
    scan_add<<<(N + 255) / 256, 256, 0, stream>>>(rowst, cursor, part, N, E);
    fill_csr<<<(E + 255) / 256, 256, 0, stream>>>(esrc_in, edst_in, cursor, esrc, E);

    const int gemm_grid = (N + 63) / 64;
    const int wave_grid = (N + 3) / 4;   // 4 waves per 256-thread block

    for (int l = 0; l < NLAYER; ++l) {
        const float* w1 = fwlin + (size_t)l * HD * HD;
        const float* b1 = fblin + (size_t)l * HD;
        const float* wm1 = fw1 + (size_t)l * HD * HD;
        const float* bm1 = fb1 + (size_t)l * HD;
        const float* wm2 = mlp_w2 + (size_t)l * HD * HD;
        const float* bm2 = mlp_b2 + (size_t)l * HD;

        // h2 = relu(bn(h) @ lin_w + lin_b)   [folded; layer0 gathers embeds]
        if (l == 0)
            gemm128<true, true, false><<<gemm_grid, 256, 0, stream>>>(
                table, x, w1, b1, buf1, nullptr, nullptr, nullptr, nullptr, N);
        else
            gemm128<false, true, false><<<gemm_grid, 256, 0, stream>>>(
                buf0, nullptr, w1, b1, buf1, nullptr, nullptr, nullptr, nullptr, N);

        // z = (1+eps)*h2 + gather-sum
        aggregate<<<wave_grid, 256, 0, stream>>>(buf1, rowst, esrc, epsv, l, buf0, N);

        // z2 = relu(bn(z @ mlp_w1 + b1))     [folded]
        gemm128<false, true, false><<<gemm_grid, 256, 0, stream>>>(
            buf0, nullptr, wm1, bm1, buf1, nullptr, nullptr, nullptr, nullptr, N);

        // h = z2 @ mlp_w2 + b2; last layer fuses readout dot + graph reduce
        if (l < NLAYER - 1)
            gemm128<false, false, false><<<gemm_grid, 256, 0, stream>>>(
                buf1, nullptr, wm2, bm2, buf0, nullptr, nullptr, nullptr, nullptr, N);
        else
            gemm128<false, false, true><<<gemm_grid, 256, 0, stream>>>(
                buf1, nullptr, wm2, bm2, nullptr, ro_w, ro_b, batch, (float*)d_out, N);
    }
}

// Round 5
// 545.580 us; speedup vs baseline: 1.4682x; 1.2335x over previous
//
#include <hip/hip_runtime.h>

// ---------------------------------------------------------------------------
// GIN forward (eval mode).
// Round-5 structure: fold BN into weights; CSR build; per layer:
//   gemm_h2 (lin GEMM + relu, layer0 gathers embeds, writes h2 as BF16)
//   -> aggregate_bf16 (gather-sum over bf16 rows, fp32 accum, fp32 z)
//   -> mlp2x (fused mlp1(relu)+mlp2 double-GEMM, LDS tile reused;
//             last layer: fused readout-dot + segmented-scan graph reduce).
// ---------------------------------------------------------------------------

#define HD 128          // hidden channels
#define NLAYER 3

// bf16 helpers (round-to-nearest-even pack, cheap unpack)
static __device__ __forceinline__ unsigned short f2bf(float f) {
    union { float f; unsigned u; } v; v.f = f;
    unsigned r = (v.u + 0x7fffu + ((v.u >> 16) & 1u)) >> 16;
    return (unsigned short)r;
}
static __device__ __forceinline__ float bf_lo(unsigned u) {
    return __uint_as_float(u << 16);
}
static __device__ __forceinline__ float bf_hi(unsigned u) {
    return __uint_as_float(u & 0xffff0000u);
}

// ---------------- prep: fold batchnorms into weights ----------------
__global__ void prep_weights(
    const float* __restrict__ bn_g, const float* __restrict__ bn_b,
    const float* __restrict__ bn_m, const float* __restrict__ bn_v,
    const float* __restrict__ lin_w, const float* __restrict__ lin_b,
    const float* __restrict__ mbn_g, const float* __restrict__ mbn_b,
    const float* __restrict__ mbn_m, const float* __restrict__ mbn_v,
    const float* __restrict__ mlp_w1, const float* __restrict__ mlp_b1,
    float* __restrict__ fwlin, float* __restrict__ fblin,
    float* __restrict__ fw1,   float* __restrict__ fb1)
{
    const int l = blockIdx.x;      // layer
    const int j = threadIdx.x;     // 128 threads = one output column each
    __shared__ float sa[HD], sc[HD];

    const int lb = l * HD;
    float a = bn_g[lb + j] * rsqrtf(bn_v[lb + j] + 1e-5f);
    float c = bn_b[lb + j] - bn_m[lb + j] * a;
    sa[j] = a; sc[j] = c;
    __syncthreads();

    // pre-BN fold: bn(h)@W + b  ==  h @ (a_k * W[k][j]) + (b[j] + sum_k c_k W[k][j])
    float accb = lin_b[lb + j];
    const int wb = l * HD * HD;
    for (int k = 0; k < HD; ++k) {
        float w = lin_w[wb + k * HD + j];
        fwlin[wb + k * HD + j] = sa[k] * w;
        accb += sc[k] * w;
    }
    fblin[lb + j] = accb;

    // post-BN fold: bn(h@W1 + b1) == h @ (a2_j W1[k][j]) + (a2_j b1[j] + c2_j)
    float a2 = mbn_g[lb + j] * rsqrtf(mbn_v[lb + j] + 1e-5f);
    float c2 = mbn_b[lb + j] - mbn_m[lb + j] * a2;
    for (int k = 0; k < HD; ++k) {
        fw1[wb + k * HD + j] = a2 * mlp_w1[wb + k * HD + j];
    }
    fb1[lb + j] = a2 * mlp_b1[lb + j] + c2;
}

// ---------------- CSR build ----------------
__global__ void count_deg(const int* __restrict__ dst, int* __restrict__ deg, int e)
{
    int i = blockIdx.x * blockDim.x + threadIdx.x;
    if (i < e) atomicAdd(&deg[dst[i]], 1);
}

__global__ void scan_blocks(const int* __restrict__ deg, int* __restrict__ excl,
                            int* __restrict__ partials, int n)
{
    __shared__ int wt[4];
    int t = threadIdx.x;
    int base = blockIdx.x * 1024 + t * 4;
    int v0 = (base + 0 < n) ? deg[base + 0] : 0;
    int v1 = (base + 1 < n) ? deg[base + 1] : 0;
    int v2 = (base + 2 < n) ? deg[base + 2] : 0;
    int v3 = (base + 3 < n) ? deg[base + 3] : 0;
    int s = v0 + v1 + v2 + v3;
    int lane = t & 63, w = t >> 6;
    int inc = s;
    #pragma unroll
    for (int d = 1; d < 64; d <<= 1) {
        int o = __shfl_up(inc, d);
        if (lane >= d) inc += o;
    }
    if (lane == 63) wt[w] = inc;
    __syncthreads();
    int off = 0;
    for (int i = 0; i < w; ++i) off += wt[i];
    int ex = off + inc - s;   // exclusive prefix of this thread's 4 elements
    if (base + 0 < n) excl[base + 0] = ex; ex += v0;
    if (base + 1 < n) excl[base + 1] = ex; ex += v1;
    if (base + 2 < n) excl[base + 2] = ex; ex += v2;
    if (base + 3 < n) excl[base + 3] = ex;
    if (t == 255) partials[blockIdx.x] = off + inc;
}

__global__ void scan_small(int* __restrict__ partials, int nb)
{
    int t = threadIdx.x;   // 64 threads, nb <= 64
    int v = (t < nb) ? partials[t] : 0;
    int inc = v;
    #pragma unroll
    for (int d = 1; d < 64; d <<= 1) {
        int o = __shfl_up(inc, d);
        if (t >= d) inc += o;
    }
    if (t < nb) partials[t] = inc - v;   // exclusive
}

__global__ void scan_add(int* __restrict__ rowst, int* __restrict__ cursor,
                         const int* __restrict__ partials, int n, int e)
{
    int idx = blockIdx.x * blockDim.x + threadIdx.x;
    if (idx < n) {
        int v = rowst[idx] + partials[idx >> 10];
        rowst[idx] = v;
        cursor[idx] = v;
    }
    if (idx == 0) rowst[n] = e;
}

__global__ void fill_csr(const int* __restrict__ src, const int* __restrict__ dst,
                         int* __restrict__ cursor, int* __restrict__ esrc, int e)
{
    int i = blockIdx.x * blockDim.x + threadIdx.x;
    if (i < e) {
        int p = atomicAdd(&cursor[dst[i]], 1);
        esrc[p] = src[i];
    }
}

// ---------------- gemm_h2: H2 = relu(X @ W + B), written as BF16 ----------
// Block: 256 threads = 4 waves. Tile: 64 rows. Wave w owns cols [32w,32w+32).
// GATHER: stage rows from X[xidx[row]] (fused embedding on layer 0).
template<bool GATHER>
__global__ __launch_bounds__(256, 4)
void gemm_h2(const float* __restrict__ X, const int* __restrict__ xidx,
             const float* __restrict__ W, const float* __restrict__ B,
             unsigned short* __restrict__ Y, int n)
{
    __shared__ float sH[64 * 129];
    const int t = threadIdx.x;
    const int lane = t & 63;
    const int cbase = __builtin_amdgcn_readfirstlane((t >> 6) << 5);
    const int tile = blockIdx.x * 64;

    for (int i = t; i < 64 * 32; i += 256) {
        int row = i >> 5, k4 = i & 31;
        float4 v = make_float4(0.f, 0.f, 0.f, 0.f);
        if (tile + row < n) {
            size_t r = GATHER ? (size_t)xidx[tile + row] : (size_t)(tile + row);
            v = reinterpret_cast<const float4*>(X)[r * 32 + k4];
        }
        float* d = &sH[row * 129 + k4 * 4];
        d[0] = v.x; d[1] = v.y; d[2] = v.z; d[3] = v.w;
    }
    __syncthreads();

    float acc[32];
    #pragma unroll
    for (int j = 0; j < 32; ++j) acc[j] = 0.f;

    const float* Wc = W + cbase;
    for (int k = 0; k < HD; ++k) {
        float hv = sH[lane * 129 + k];
        const float* wr = Wc + k * HD;       // uniform -> s_load
        #pragma unroll
        for (int j = 0; j < 32; ++j) acc[j] = fmaf(hv, wr[j], acc[j]);
    }

    int row = tile + lane;
    if (row < n) {
        // pack 32 relu'd bf16 -> 4x uint4 stores (16B each)
        uint4 o[4];
        unsigned* ow = reinterpret_cast<unsigned*>(o);
        #pragma unroll
        for (int p = 0; p < 16; ++p) {
            float v0 = fmaxf(acc[2 * p]     + B[cbase + 2 * p],     0.f);
            float v1 = fmaxf(acc[2 * p + 1] + B[cbase + 2 * p + 1], 0.f);
            ow[p] = (unsigned)f2bf(v0) | ((unsigned)f2bf(v1) << 16);
        }
        uint4* yr = reinterpret_cast<uint4*>(
            reinterpret_cast<unsigned short*>(Y) + (size_t)row * HD + cbase);
        #pragma unroll
        for (int p = 0; p < 4; ++p) yr[p] = o[p];
    }
}

// ---------------- aggregation: z = (1+eps)*h2 + sum in-edge h2[src], bf16 in --
__global__ void aggregate_bf16(const unsigned short* __restrict__ h2b,
                               const int* __restrict__ rowst,
                               const int* __restrict__ esrc,
                               const float* __restrict__ epsp,
                               int layer, float* __restrict__ z, int n)
{
    int gw = (blockIdx.x * blockDim.x + threadIdx.x) >> 6;   // one wave per node
    int lane = threadIdx.x & 63;
    if (gw >= n) return;
    float se = 1.0f + epsp[layer];
    int rs = __builtin_amdgcn_readfirstlane(rowst[gw]);
    int re = __builtin_amdgcn_readfirstlane(rowst[gw + 1]);
    const unsigned* hv = reinterpret_cast<const unsigned*>(h2b);  // 2 bf16/elem
    unsigned su = hv[(size_t)gw * 64 + lane];
    float ax0 = se * bf_lo(su), ay0 = se * bf_hi(su);
    float ax1 = 0.f, ay1 = 0.f, ax2 = 0.f, ay2 = 0.f, ax3 = 0.f, ay3 = 0.f;
    for (int base = rs; base < re; base += 64) {
        int cnt = re - base; if (cnt > 64) cnt = 64;
        int eid = (base + lane < re) ? esrc[base + lane] : 0;
        int j = 0;
        for (; j + 4 <= cnt; j += 4) {
            int s0 = __shfl(eid, j + 0);
            int s1 = __shfl(eid, j + 1);
            int s2 = __shfl(eid, j + 2);
            int s3 = __shfl(eid, j + 3);
            unsigned u0 = hv[(size_t)s0 * 64 + lane];
            unsigned u1 = hv[(size_t)s1 * 64 + lane];
            unsigned u2 = hv[(size_t)s2 * 64 + lane];
            unsigned u3 = hv[(size_t)s3 * 64 + lane];
            ax0 += bf_lo(u0); ay0 += bf_hi(u0);
            ax1 += bf_lo(u1); ay1 += bf_hi(u1);
            ax2 += bf_lo(u2); ay2 += bf_hi(u2);
            ax3 += bf_lo(u3); ay3 += bf_hi(u3);
        }
        for (; j < cnt; ++j) {
            int s0 = __shfl(eid, j);
            unsigned u0 = hv[(size_t)s0 * 64 + lane];
            ax0 += bf_lo(u0); ay0 += bf_hi(u0);
        }
    }
    float2 o;
    o.x = (ax0 + ax1) + (ax2 + ax3);
    o.y = (ay0 + ay1) + (ay2 + ay3);
    reinterpret_cast<float2*>(z)[(size_t)gw * 64 + lane] = o;
}

// ---------------- mlp2x: H = relu(Z@W1+B1)@W2+B2, fused double GEMM --------
// LDS tile reused: stage Z -> GEMM1 -> sync -> overwrite tile with z2 ->
// sync -> GEMM2. FUSE_RO: last layer, no H write; readout dot + segmented
// scan over sorted batch -> few atomics into gout.
template<bool FUSE_RO>
__global__ __launch_bounds__(256, 4)
void mlp2x(const float* __restrict__ Z,
           const float* __restrict__ W1, const float* __restrict__ B1,
           const float* __restrict__ W2, const float* __restrict__ B2,
           float* __restrict__ H,
           const float* __restrict__ rw, const float* __restrict__ rb,
           const int* __restrict__ batch, float* __restrict__ gout,
           int n)
{
    __shared__ float sH[64 * 129];
    __shared__ float sD[64][4];
    const int t = threadIdx.x;
    const int lane = t & 63;
    const int wv = t >> 6;
    const int cbase = __builtin_amdgcn_readfirstlane(wv << 5);
    const int tile = blockIdx.x * 64;

    for (int i = t; i < 64 * 32; i += 256) {
        int row = i >> 5, k4 = i & 31;
        float4 v = make_float4(0.f, 0.f, 0.f, 0.f);
        if (tile + row < n)
            v = reinterpret_cast<const float4*>(Z)[(size_t)(tile + row) * 32 + k4];
        float* d = &sH[row * 129 + k4 * 4];
        d[0] = v.x; d[1] = v.y; d[2] = v.z; d[3] = v.w;
    }
    __syncthreads();

    float acc[32];
    #pragma unroll
    for (int j = 0; j < 32; ++j) acc[j] = 0.f;

    const float* W1c = W1 + cbase;
    for (int k = 0; k < HD; ++k) {
        float hv = sH[lane * 129 + k];
        const float* wr = W1c + k * HD;
        #pragma unroll
        for (int j = 0; j < 32; ++j) acc[j] = fmaf(hv, wr[j], acc[j]);
    }
    #pragma unroll
    for (int j = 0; j < 32; ++j) acc[j] = fmaxf(acc[j] + B1[cbase + j], 0.f);

    __syncthreads();   // all GEMM1 reads of sH complete
    // write z2 tile back into sH: row=lane, cols [cbase, cbase+32)
    #pragma unroll
    for (int j = 0; j < 32; ++j) sH[lane * 129 + cbase + j] = acc[j];
    __syncthreads();

    float acc2[32];
    #pragma unroll
    for (int j = 0; j < 32; ++j) acc2[j] = 0.f;

    const float* W2c = W2 + cbase;
    for (int k = 0; k < HD; ++k) {
        float hv = sH[lane * 129 + k];
        const float* wr = W2c + k * HD;
        #pragma unroll
        for (int j = 0; j < 32; ++j) acc2[j] = fmaf(hv, wr[j], acc2[j]);
    }

    if (!FUSE_RO) {
        int row = tile + lane;
        if (row < n) {
            float* yr = H + (size_t)row * HD + cbase;
            #pragma unroll
            for (int j = 0; j < 32; ++j) yr[j] = acc2[j] + B2[cbase + j];
        }
    } else {
        float part = 0.f;
        #pragma unroll
        for (int j = 0; j < 32; ++j)
            part = fmaf(acc2[j] + B2[cbase + j], rw[cbase + j], part);
        sD[lane][wv] = part;
        __syncthreads();
        if (t < 64) {                         // wave 0 flushes 64 rows
            int row = tile + t;
            float v = sD[t][0] + sD[t][1] + sD[t][2] + sD[t][3] + rb[0];
            int b = (row < n) ? batch[row] : -1;
            if (row >= n) v = 0.f;
            #pragma unroll
            for (int d = 1; d < 64; d <<= 1) {
                int   ob = __shfl_up(b, d);
                float ov = __shfl_up(v, d);
                if (t >= d && ob == b) v += ov;
            }
            int nb2 = __shfl_down(b, 1);
            bool lastl = (t == 63) || (nb2 != b);
            if (lastl && b >= 0) atomicAdd(&gout[b], v);
        }
    }
}

// ---------------------------------------------------------------------------
extern "C" void kernel_launch(void* const* d_in, const int* in_sizes, int n_in,
                              void* d_out, int out_size, void* d_ws, size_t ws_size,
                              hipStream_t stream)
{
    const int N = in_sizes[0];          // 50000
    const int E = in_sizes[1] / 2;      // 800000
    const int G = out_size;             // 512

    const int*   x      = (const int*)d_in[0];
    const int*   ei     = (const int*)d_in[1];
    const int*   batch  = (const int*)d_in[2];
    const float* table  = (const float*)d_in[3];
    const float* bn_g   = (const float*)d_in[4];
    const float* bn_b   = (const float*)d_in[5];
    const float* bn_m   = (const float*)d_in[6];
    const float* bn_v   = (const float*)d_in[7];
    const float* lin_w  = (const float*)d_in[8];
    const float* lin_b  = (const float*)d_in[9];
    const float* epsv   = (const float*)d_in[10];
    const float* mlp_w1 = (const float*)d_in[11];
    const float* mlp_b1 = (const float*)d_in[12];
    const float* mbn_g  = (const float*)d_in[13];
    const float* mbn_b  = (const float*)d_in[14];
    const float* mbn_m  = (const float*)d_in[15];
    const float* mbn_v  = (const float*)d_in[16];
    const float* mlp_w2 = (const float*)d_in[17];
    const float* mlp_b2 = (const float*)d_in[18];
    const float* ro_w   = (const float*)d_in[19];
    const float* ro_b   = (const float*)d_in[20];

    const int* esrc_in = ei;        // edge_index[0]
    const int* edst_in = ei + E;    // edge_index[1]

    // ---- workspace carve-up (all offsets 256B aligned) ----
    char* w = (char*)d_ws;
    size_t off = 0;
    auto alloc = [&](size_t bytes) {
        void* p = w + off;
        off += (bytes + 255) & ~(size_t)255;
        return p;
    };
    float*          buf0  = (float*)alloc((size_t)N * HD * 4);          // h / z (fp32)
    unsigned short* h2b   = (unsigned short*)alloc((size_t)N * HD * 2); // bf16 h2
    float* fwlin  = (float*)alloc((size_t)NLAYER * HD * HD * 4);
    float* fblin  = (float*)alloc((size_t)NLAYER * HD * 4);
    float* fw1    = (float*)alloc((size_t)NLAYER * HD * HD * 4);
    float* fb1    = (float*)alloc((size_t)NLAYER * HD * 4);
    int*   deg    = (int*)alloc((size_t)N * 4);
    int*   rowst  = (int*)alloc((size_t)(N + 1) * 4);
    int*   cursor = (int*)alloc((size_t)N * 4);
    int*   esrc   = (int*)alloc((size_t)E * 4);
    int*   part   = (int*)alloc(256 * 4);
    (void)ws_size;

    hipMemsetAsync(deg, 0, (size_t)N * 4, stream);
    hipMemsetAsync(d_out, 0, (size_t)G * 4, stream);

    prep_weights<<<NLAYER, HD, 0, stream>>>(bn_g, bn_b, bn_m, bn_v, lin_w, lin_b,
                                            mbn_g, mbn_b, mbn_m, mbn_v, mlp_w1, mlp_b1,
                                            fwlin, fblin, fw1, fb1);

    count_deg<<<(E + 255) / 256, 256, 0, stream>>>(edst_in, deg, E);
    int nb = (N + 1023) / 1024;
    scan_blocks<<<nb, 256, 0, stream>>>(deg, rowst, part, N);
    scan_small<<<1, 64, 0, stream>>>(part, nb);
    scan_add<<<(N + 255) / 256, 256, 0, stream>>>(rowst, cursor, part, N, E);
    fill_csr<<<(E + 255) / 256, 256, 0, stream>>>(esrc_in, edst_in, cursor, esrc, E);

    const int gemm_grid = (N + 63) / 64;
    const int wave_grid = (N + 3) / 4;   // 4 waves per 256-thread block

    for (int l = 0; l < NLAYER; ++l) {
        const float* w1  = fwlin + (size_t)l * HD * HD;
        const float* b1  = fblin + (size_t)l * HD;
        const float* wm1 = fw1 + (size_t)l * HD * HD;
        const float* bm1 = fb1 + (size_t)l * HD;
        const float* wm2 = mlp_w2 + (size_t)l * HD * HD;
        const float* bm2 = mlp_b2 + (size_t)l * HD;

        // h2 = relu(bn(h) @ lin_w + lin_b)  [folded] -> bf16
        if (l == 0)
            gemm_h2<true><<<gemm_grid, 256, 0, stream>>>(table, x, w1, b1, h2b, N);
        else
            gemm_h2<false><<<gemm_grid, 256, 0, stream>>>(buf0, nullptr, w1, b1, h2b, N);

        // z = (1+eps)*h2 + gather-sum   (bf16 reads, fp32 accumulate/write)
        aggregate_bf16<<<wave_grid, 256, 0, stream>>>(h2b, rowst, esrc, epsv, l, buf0, N);

        // h = relu(z@W1+b1)@W2+b2  (fused; last layer fuses readout)
        if (l < NLAYER - 1)
            mlp2x<false><<<gemm_grid, 256, 0, stream>>>(
                buf0, wm1, bm1, wm2, bm2, buf0,
                nullptr, nullptr, nullptr, nullptr, N);
        else
            mlp2x<true><<<gemm_grid, 256, 0, stream>>>(
                buf0, wm1, bm1, wm2, bm2, nullptr,
                ro_w, ro_b, batch, (float*)d_out, N);
    }
}

// Round 6
// 422.234 us; speedup vs baseline: 1.8971x; 1.2921x over previous
//
#include <hip/hip_runtime.h>
#include <hip/hip_fp16.h>

// ---------------------------------------------------------------------------
// GIN forward (eval mode), fp16-MFMA version.
// prep: fold BN into weights, transpose to [n][k] f16.
// per layer: lin_mfma (MFMA GEMM + relu -> h2 f16; layer0 gathers embeds)
//            -> aggregate_f16 (CSR gather-sum, f32 accum, f16 z)
//            -> mlp_mfma (fused GEMM1(relu)+GEMM2 via LDS z2 handoff;
//               last layer: readout dot + segmented-scan graph reduce).
// ---------------------------------------------------------------------------

#define HD 128
#define NLAYER 3
#define PITCH 136   // f16 units per LDS row (272 B = 17 x 16 B chunks)

typedef _Float16 half8 __attribute__((ext_vector_type(8)));
typedef float    f32x4 __attribute__((ext_vector_type(4)));

// ---------------- prep: fold BN, convert + transpose weights to f16 --------
__global__ void prep_weights(
    const float* __restrict__ bn_g, const float* __restrict__ bn_b,
    const float* __restrict__ bn_m, const float* __restrict__ bn_v,
    const float* __restrict__ lin_w, const float* __restrict__ lin_b,
    const float* __restrict__ mbn_g, const float* __restrict__ mbn_b,
    const float* __restrict__ mbn_m, const float* __restrict__ mbn_v,
    const float* __restrict__ mlp_w1, const float* __restrict__ mlp_b1,
    const float* __restrict__ mlp_w2,
    _Float16* __restrict__ wtl, float* __restrict__ fbl,
    _Float16* __restrict__ wt1, float* __restrict__ fb1,
    _Float16* __restrict__ wt2)
{
    const int l = blockIdx.x;
    const int t = threadIdx.x;          // 128 threads
    __shared__ float sa[HD], sc[HD], sa2[HD];

    const int lb = l * HD;
    const int wb = l * HD * HD;
    float a  = bn_g[lb + t] * rsqrtf(bn_v[lb + t] + 1e-5f);
    float c  = bn_b[lb + t] - bn_m[lb + t] * a;
    float a2 = mbn_g[lb + t] * rsqrtf(mbn_v[lb + t] + 1e-5f);
    float c2 = mbn_b[lb + t] - mbn_m[lb + t] * a2;
    sa[t] = a; sc[t] = c; sa2[t] = a2;
    __syncthreads();

    // bias folds (thread t = output col j), coalesced reads
    float accb = lin_b[lb + t];
    for (int k = 0; k < HD; ++k) accb += sc[k] * lin_w[wb + k * HD + t];
    fbl[lb + t] = accb;
    fb1[lb + t] = a2 * mlp_b1[lb + t] + c2;

    // transposed f16 weights: Wt[j][k]; thread t = k, loop j -> coalesced writes
    for (int j = 0; j < HD; ++j) {
        wtl[wb + j * HD + t] = (_Float16)(sa[t] * lin_w[wb + t * HD + j]);
        wt1[wb + j * HD + t] = (_Float16)(sa2[j] * mlp_w1[wb + t * HD + j]);
        wt2[wb + j * HD + t] = (_Float16)(mlp_w2[wb + t * HD + j]);
    }
}

// ---------------- CSR build ----------------
__global__ void count_deg(const int* __restrict__ dst, int* __restrict__ deg, int e)
{
    int i = blockIdx.x * blockDim.x + threadIdx.x;
    if (i < e) atomicAdd(&deg[dst[i]], 1);
}

__global__ void scan_blocks(const int* __restrict__ deg, int* __restrict__ excl,
                            int* __restrict__ partials, int n)
{
    __shared__ int wt[4];
    int t = threadIdx.x;
    int base = blockIdx.x * 1024 + t * 4;
    int v0 = (base + 0 < n) ? deg[base + 0] : 0;
    int v1 = (base + 1 < n) ? deg[base + 1] : 0;
    int v2 = (base + 2 < n) ? deg[base + 2] : 0;
    int v3 = (base + 3 < n) ? deg[base + 3] : 0;
    int s = v0 + v1 + v2 + v3;
    int lane = t & 63, w = t >> 6;
    int inc = s;
    #pragma unroll
    for (int d = 1; d < 64; d <<= 1) {
        int o = __shfl_up(inc, d);
        if (lane >= d) inc += o;
    }
    if (lane == 63) wt[w] = inc;
    __syncthreads();
    int off = 0;
    for (int i = 0; i < w; ++i) off += wt[i];
    int ex = off + inc - s;
    if (base + 0 < n) excl[base + 0] = ex; ex += v0;
    if (base + 1 < n) excl[base + 1] = ex; ex += v1;
    if (base + 2 < n) excl[base + 2] = ex; ex += v2;
    if (base + 3 < n) excl[base + 3] = ex;
    if (t == 255) partials[blockIdx.x] = off + inc;
}

__global__ void scan_small(int* __restrict__ partials, int nb)
{
    int t = threadIdx.x;
    int v = (t < nb) ? partials[t] : 0;
    int inc = v;
    #pragma unroll
    for (int d = 1; d < 64; d <<= 1) {
        int o = __shfl_up(inc, d);
        if (t >= d) inc += o;
    }
    if (t < nb) partials[t] = inc - v;
}

__global__ void scan_add(int* __restrict__ rowst, int* __restrict__ cursor,
                         const int* __restrict__ partials, int n, int e)
{
    int idx = blockIdx.x * blockDim.x + threadIdx.x;
    if (idx < n) {
        int v = rowst[idx] + partials[idx >> 10];
        rowst[idx] = v;
        cursor[idx] = v;
    }
    if (idx == 0) rowst[n] = e;
}

__global__ void fill_csr(const int* __restrict__ src, const int* __restrict__ dst,
                         int* __restrict__ cursor, int* __restrict__ esrc, int e)
{
    int i = blockIdx.x * blockDim.x + threadIdx.x;
    if (i < e) {
        int p = atomicAdd(&cursor[dst[i]], 1);
        esrc[p] = src[i];
    }
}

// ---------------- lin_mfma: H2 = relu(X @ W + B) -> f16 --------------------
// 64-row tile, 4 waves in 2x2 (rowhalf x colhalf). A staged in LDS (272B
// pitch). B-frags (16 x half8) held in VGPRs from transposed f16 W (L2-res).
template<bool GATHER>
__global__ __launch_bounds__(256, 3)
void lin_mfma(const float* __restrict__ Xf, const _Float16* __restrict__ Xh,
              const int* __restrict__ xidx,
              const _Float16* __restrict__ Wt, const float* __restrict__ B,
              _Float16* __restrict__ Y, int n)
{
    __shared__ __align__(16) _Float16 sA[64 * PITCH];
    const int t = threadIdx.x;
    const int lane = t & 63;
    const int w = t >> 6;
    const int rw_ = w >> 1, cw = w & 1;
    const int m = lane & 15, g = lane >> 4;
    const int tile = blockIdx.x * 64;

    // ---- stage A tile: thread -> row t>>2, 32-col quarter t&3 ----
    {
        int row = t >> 2, q = t & 3;
        int gr = tile + row;
        _Float16* dst = &sA[row * PITCH + q * 32];
        if (GATHER) {
            if (gr < n) {
                int id = xidx[gr];
                const float4* src = reinterpret_cast<const float4*>(Xf + (size_t)id * HD) + q * 8;
                #pragma unroll
                for (int c = 0; c < 4; ++c) {
                    float4 va = src[2 * c], vb = src[2 * c + 1];
                    half8 h = {(_Float16)va.x, (_Float16)va.y, (_Float16)va.z, (_Float16)va.w,
                               (_Float16)vb.x, (_Float16)vb.y, (_Float16)vb.z, (_Float16)vb.w};
                    *reinterpret_cast<half8*>(dst + c * 8) = h;
                }
            } else {
                half8 zz = {0, 0, 0, 0, 0, 0, 0, 0};
                #pragma unroll
                for (int c = 0; c < 4; ++c) *reinterpret_cast<half8*>(dst + c * 8) = zz;
            }
        } else {
            half8 zz = {0, 0, 0, 0, 0, 0, 0, 0};
            const half8* src = reinterpret_cast<const half8*>(Xh + (size_t)gr * HD + q * 32);
            #pragma unroll
            for (int c = 0; c < 4; ++c)
                *reinterpret_cast<half8*>(dst + c * 8) = (gr < n) ? src[c] : zz;
        }
    }
    __syncthreads();

    // ---- B fragments: wave covers col-tiles ct = 4*cw .. 4*cw+3 ----
    half8 bf[4][4];   // [ct4][kk]
    #pragma unroll
    for (int ct4 = 0; ct4 < 4; ++ct4) {
        int ct = 4 * cw + ct4;
        #pragma unroll
        for (int kk = 0; kk < 4; ++kk)
            bf[ct4][kk] = *reinterpret_cast<const half8*>(
                Wt + (size_t)(16 * ct + m) * HD + kk * 32 + g * 8);
    }

    f32x4 acc[2][4];
    #pragma unroll
    for (int i = 0; i < 2; ++i)
        #pragma unroll
        for (int j = 0; j < 4; ++j) acc[i][j] = (f32x4){0.f, 0.f, 0.f, 0.f};

    #pragma unroll
    for (int rg2 = 0; rg2 < 2; ++rg2) {
        int rg = 2 * rw_ + rg2;
        #pragma unroll
        for (int kk = 0; kk < 4; ++kk) {
            half8 a = *reinterpret_cast<const half8*>(
                &sA[(16 * rg + m) * PITCH + kk * 32 + g * 8]);
            #pragma unroll
            for (int ct4 = 0; ct4 < 4; ++ct4)
                acc[rg2][ct4] = __builtin_amdgcn_mfma_f32_16x16x32_f16(
                    a, bf[ct4][kk], acc[rg2][ct4], 0, 0, 0);
        }
    }

    // ---- epilogue: bias + relu + f16 stores ----
    #pragma unroll
    for (int rg2 = 0; rg2 < 2; ++rg2) {
        int rg = 2 * rw_ + rg2;
        #pragma unroll
        for (int ct4 = 0; ct4 < 4; ++ct4) {
            int col = 16 * (4 * cw + ct4) + m;
            float bb = B[col];
            #pragma unroll
            for (int reg = 0; reg < 4; ++reg) {
                int r = tile + 16 * rg + 4 * g + reg;
                if (r < n) {
                    float v = fmaxf(acc[rg2][ct4][reg] + bb, 0.f);
                    Y[(size_t)r * HD + col] = (_Float16)v;
                }
            }
        }
    }
}

// ---------------- aggregate: z = (1+eps)*h2 + sum in-edge h2[src], f16 -----
__global__ void aggregate_f16(const _Float16* __restrict__ h2,
                              const int* __restrict__ rowst,
                              const int* __restrict__ esrc,
                              const float* __restrict__ epsp,
                              int layer, _Float16* __restrict__ z, int n)
{
    int gw = (blockIdx.x * blockDim.x + threadIdx.x) >> 6;
    int lane = threadIdx.x & 63;
    if (gw >= n) return;
    float se = 1.0f + epsp[layer];
    int rs = __builtin_amdgcn_readfirstlane(rowst[gw]);
    int re = __builtin_amdgcn_readfirstlane(rowst[gw + 1]);
    const half2* hv = reinterpret_cast<const half2*>(h2);
    float2 s = __half22float2(hv[(size_t)gw * 64 + lane]);
    float ax0 = se * s.x, ay0 = se * s.y;
    float ax1 = 0.f, ay1 = 0.f, ax2 = 0.f, ay2 = 0.f, ax3 = 0.f, ay3 = 0.f;
    for (int base = rs; base < re; base += 64) {
        int cnt = re - base; if (cnt > 64) cnt = 64;
        int eid = (base + lane < re) ? esrc[base + lane] : 0;
        int j = 0;
        for (; j + 4 <= cnt; j += 4) {
            int s0 = __shfl(eid, j + 0);
            int s1 = __shfl(eid, j + 1);
            int s2 = __shfl(eid, j + 2);
            int s3 = __shfl(eid, j + 3);
            float2 v0 = __half22float2(hv[(size_t)s0 * 64 + lane]);
            float2 v1 = __half22float2(hv[(size_t)s1 * 64 + lane]);
            float2 v2 = __half22float2(hv[(size_t)s2 * 64 + lane]);
            float2 v3 = __half22float2(hv[(size_t)s3 * 64 + lane]);
            ax0 += v0.x; ay0 += v0.y;
            ax1 += v1.x; ay1 += v1.y;
            ax2 += v2.x; ay2 += v2.y;
            ax3 += v3.x; ay3 += v3.y;
        }
        for (; j < cnt; ++j) {
            int s0 = __shfl(eid, j);
            float2 v0 = __half22float2(hv[(size_t)s0 * 64 + lane]);
            ax0 += v0.x; ay0 += v0.y;
        }
    }
    float ox = (ax0 + ax1) + (ax2 + ax3);
    float oy = (ay0 + ay1) + (ay2 + ay3);
    reinterpret_cast<half2*>(z)[(size_t)gw * 64 + lane] = __floats2half2_rn(ox, oy);
}

// ---------------- mlp_mfma: H = relu(Z@W1+B1)@W2+B2 (fused 2x MFMA GEMM) --
// z2 handoff through the same LDS A-buffer (scatter f16 [row][col], 272B
// pitch). FUSE_RO: readout dot + segmented scan instead of H write.
template<bool FUSE_RO>
__global__ __launch_bounds__(256, 3)
void mlp_mfma(const _Float16* __restrict__ Z,
              const _Float16* __restrict__ Wt1, const float* __restrict__ B1,
              const _Float16* __restrict__ Wt2, const float* __restrict__ B2,
              _Float16* __restrict__ H,
              const float* __restrict__ rw, const float* __restrict__ rb,
              const int* __restrict__ batch, float* __restrict__ gout, int n)
{
    __shared__ __align__(16) _Float16 sA[64 * PITCH];
    __shared__ float sD[64][2];
    const int t = threadIdx.x;
    const int lane = t & 63;
    const int w = t >> 6;
    const int rw_ = w >> 1, cw = w & 1;
    const int m = lane & 15, g = lane >> 4;
    const int tile = blockIdx.x * 64;

    // ---- stage Z tile ----
    {
        int row = t >> 2, q = t & 3;
        int gr = tile + row;
        _Float16* dst = &sA[row * PITCH + q * 32];
        half8 zz = {0, 0, 0, 0, 0, 0, 0, 0};
        const half8* src = reinterpret_cast<const half8*>(Z + (size_t)gr * HD + q * 32);
        #pragma unroll
        for (int c = 0; c < 4; ++c)
            *reinterpret_cast<half8*>(dst + c * 8) = (gr < n) ? src[c] : zz;
    }
    __syncthreads();

    // ---- GEMM1 ----
    half8 bf[4][4];
    #pragma unroll
    for (int ct4 = 0; ct4 < 4; ++ct4) {
        int ct = 4 * cw + ct4;
        #pragma unroll
        for (int kk = 0; kk < 4; ++kk)
            bf[ct4][kk] = *reinterpret_cast<const half8*>(
                Wt1 + (size_t)(16 * ct + m) * HD + kk * 32 + g * 8);
    }
    f32x4 acc[2][4];
    #pragma unroll
    for (int i = 0; i < 2; ++i)
        #pragma unroll
        for (int j = 0; j < 4; ++j) acc[i][j] = (f32x4){0.f, 0.f, 0.f, 0.f};
    #pragma unroll
    for (int rg2 = 0; rg2 < 2; ++rg2) {
        int rg = 2 * rw_ + rg2;
        #pragma unroll
        for (int kk = 0; kk < 4; ++kk) {
            half8 a = *reinterpret_cast<const half8*>(
                &sA[(16 * rg + m) * PITCH + kk * 32 + g * 8]);
            #pragma unroll
            for (int ct4 = 0; ct4 < 4; ++ct4)
                acc[rg2][ct4] = __builtin_amdgcn_mfma_f32_16x16x32_f16(
                    a, bf[ct4][kk], acc[rg2][ct4], 0, 0, 0);
        }
    }
    __syncthreads();   // all GEMM1 A-reads complete

    // ---- z2 = relu(acc + B1) scattered back into sA ----
    #pragma unroll
    for (int rg2 = 0; rg2 < 2; ++rg2) {
        int rg = 2 * rw_ + rg2;
        #pragma unroll
        for (int ct4 = 0; ct4 < 4; ++ct4) {
            int col = 16 * (4 * cw + ct4) + m;
            float bb = B1[col];
            #pragma unroll
            for (int reg = 0; reg < 4; ++reg) {
                int lr = 16 * rg + 4 * g + reg;
                sA[lr * PITCH + col] = (_Float16)fmaxf(acc[rg2][ct4][reg] + bb, 0.f);
            }
        }
    }
    __syncthreads();

    // ---- GEMM2 ----
    #pragma unroll
    for (int ct4 = 0; ct4 < 4; ++ct4) {
        int ct = 4 * cw + ct4;
        #pragma unroll
        for (int kk = 0; kk < 4; ++kk)
            bf[ct4][kk] = *reinterpret_cast<const half8*>(
                Wt2 + (size_t)(16 * ct + m) * HD + kk * 32 + g * 8);
    }
    f32x4 acc2[2][4];
    #pragma unroll
    for (int i = 0; i < 2; ++i)
        #pragma unroll
        for (int j = 0; j < 4; ++j) acc2[i][j] = (f32x4){0.f, 0.f, 0.f, 0.f};
    #pragma unroll
    for (int rg2 = 0; rg2 < 2; ++rg2) {
        int rg = 2 * rw_ + rg2;
        #pragma unroll
        for (int kk = 0; kk < 4; ++kk) {
            half8 a = *reinterpret_cast<const half8*>(
                &sA[(16 * rg + m) * PITCH + kk * 32 + g * 8]);
            #pragma unroll
            for (int ct4 = 0; ct4 < 4; ++ct4)
                acc2[rg2][ct4] = __builtin_amdgcn_mfma_f32_16x16x32_f16(
                    a, bf[ct4][kk], acc2[rg2][ct4], 0, 0, 0);
        }
    }

    if (!FUSE_RO) {
        #pragma unroll
        for (int rg2 = 0; rg2 < 2; ++rg2) {
            int rg = 2 * rw_ + rg2;
            #pragma unroll
            for (int ct4 = 0; ct4 < 4; ++ct4) {
                int col = 16 * (4 * cw + ct4) + m;
                float bb = B2[col];
                #pragma unroll
                for (int reg = 0; reg < 4; ++reg) {
                    int r = tile + 16 * rg + 4 * g + reg;
                    if (r < n)
                        H[(size_t)r * HD + col] = (_Float16)(acc2[rg2][ct4][reg] + bb);
                }
            }
        }
    } else {
        // per-row readout partials over this wave's 64 cols
        #pragma unroll
        for (int rg2 = 0; rg2 < 2; ++rg2) {
            int rg = 2 * rw_ + rg2;
            float pr[4] = {0.f, 0.f, 0.f, 0.f};
            #pragma unroll
            for (int ct4 = 0; ct4 < 4; ++ct4) {
                int col = 16 * (4 * cw + ct4) + m;
                float bb = B2[col], rr = rw[col];
                #pragma unroll
                for (int reg = 0; reg < 4; ++reg)
                    pr[reg] = fmaf(acc2[rg2][ct4][reg] + bb, rr, pr[reg]);
            }
            #pragma unroll
            for (int reg = 0; reg < 4; ++reg) {
                #pragma unroll
                for (int d = 1; d < 16; d <<= 1) pr[reg] += __shfl_xor(pr[reg], d);
            }
            if (m == 0) {
                #pragma unroll
                for (int reg = 0; reg < 4; ++reg)
                    sD[16 * rg + 4 * g + reg][cw] = pr[reg];
            }
        }
        __syncthreads();
        if (t < 64) {
            int row = tile + t;
            float v = sD[t][0] + sD[t][1] + rb[0];
            int b = (row < n) ? batch[row] : -1;
            if (row >= n) v = 0.f;
            #pragma unroll
            for (int d = 1; d < 64; d <<= 1) {
                int   ob = __shfl_up(b, d);
                float ov = __shfl_up(v, d);
                if (t >= d && ob == b) v += ov;
            }
            int nb2 = __shfl_down(b, 1);
            bool lastl = (t == 63) || (nb2 != b);
            if (lastl && b >= 0) atomicAdd(&gout[b], v);
        }
    }
}

// ---------------------------------------------------------------------------
extern "C" void kernel_launch(void* const* d_in, const int* in_sizes, int n_in,
                              void* d_out, int out_size, void* d_ws, size_t ws_size,
                              hipStream_t stream)
{
    const int N = in_sizes[0];
    const int E = in_sizes[1] / 2;
    const int G = out_size;

    const int*   x      = (const int*)d_in[0];
    const int*   ei     = (const int*)d_in[1];
    const int*   batch  = (const int*)d_in[2];
    const float* table  = (const float*)d_in[3];
    const float* bn_g   = (const float*)d_in[4];
    const float* bn_b   = (const float*)d_in[5];
    const float* bn_m   = (const float*)d_in[6];
    const float* bn_v   = (const float*)d_in[7];
    const float* lin_w  = (const float*)d_in[8];
    const float* lin_b  = (const float*)d_in[9];
    const float* epsv   = (const float*)d_in[10];
    const float* mlp_w1 = (const float*)d_in[11];
    const float* mlp_b1 = (const float*)d_in[12];
    const float* mbn_g  = (const float*)d_in[13];
    const float* mbn_b  = (const float*)d_in[14];
    const float* mbn_m  = (const float*)d_in[15];
    const float* mbn_v  = (const float*)d_in[16];
    const float* mlp_w2 = (const float*)d_in[17];
    const float* mlp_b2 = (const float*)d_in[18];
    const float* ro_w   = (const float*)d_in[19];
    const float* ro_b   = (const float*)d_in[20];

    const int* esrc_in = ei;
    const int* edst_in = ei + E;

    char* wsp = (char*)d_ws;
    size_t off = 0;
    auto alloc = [&](size_t bytes) {
        void* p = wsp + off;
        off += (bytes + 255) & ~(size_t)255;
        return p;
    };
    _Float16* bufA  = (_Float16*)alloc((size_t)N * HD * 2);  // h / z
    _Float16* bufB  = (_Float16*)alloc((size_t)N * HD * 2);  // h2
    _Float16* wtl   = (_Float16*)alloc((size_t)NLAYER * HD * HD * 2);
    _Float16* wt1   = (_Float16*)alloc((size_t)NLAYER * HD * HD * 2);
    _Float16* wt2   = (_Float16*)alloc((size_t)NLAYER * HD * HD * 2);
    float*    fbl   = (float*)alloc((size_t)NLAYER * HD * 4);
    float*    fb1   = (float*)alloc((size_t)NLAYER * HD * 4);
    int*      deg   = (int*)alloc((size_t)N * 4);
    int*      rowst = (int*)alloc((size_t)(N + 1) * 4);
    int*      cursor= (int*)alloc((size_t)N * 4);
    int*      esrc  = (int*)alloc((size_t)E * 4);
    int*      part  = (int*)alloc(256 * 4);
    (void)ws_size;

    hipMemsetAsync(deg, 0, (size_t)N * 4, stream);
    hipMemsetAsync(d_out, 0, (size_t)G * 4, stream);

    prep_weights<<<NLAYER, HD, 0, stream>>>(
        bn_g, bn_b, bn_m, bn_v, lin_w, lin_b,
        mbn_g, mbn_b, mbn_m, mbn_v, mlp_w1, mlp_b1, mlp_w2,
        wtl, fbl, wt1, fb1, wt2);

    count_deg<<<(E + 255) / 256, 256, 0, stream>>>(edst_in, deg, E);
    int nb = (N + 1023) / 1024;
    scan_blocks<<<nb, 256, 0, stream>>>(deg, rowst, part, N);
    scan_small<<<1, 64, 0, stream>>>(part, nb);
    scan_add<<<(N + 255) / 256, 256, 0, stream>>>(rowst, cursor, part, N, E);
    fill_csr<<<(E + 255) / 256, 256, 0, stream>>>(esrc_in, edst_in, cursor, esrc, E);

    const int gemm_grid = (N + 63) / 64;
    const int wave_grid = (N + 3) / 4;

    for (int l = 0; l < NLAYER; ++l) {
        const _Float16* wl = wtl + (size_t)l * HD * HD;
        const float*    bl = fbl + (size_t)l * HD;
        const _Float16* w1 = wt1 + (size_t)l * HD * HD;
        const float*    b1 = fb1 + (size_t)l * HD;
        const _Float16* w2 = wt2 + (size_t)l * HD * HD;
        const float*    b2 = mlp_b2 + (size_t)l * HD;

        if (l == 0)
            lin_mfma<true><<<gemm_grid, 256, 0, stream>>>(
                table, nullptr, x, wl, bl, bufB, N);
        else
            lin_mfma<false><<<gemm_grid, 256, 0, stream>>>(
                nullptr, bufA, nullptr, wl, bl, bufB, N);

        aggregate_f16<<<wave_grid, 256, 0, stream>>>(
            bufB, rowst, esrc, epsv, l, bufA, N);

        if (l < NLAYER - 1)
            mlp_mfma<false><<<gemm_grid, 256, 0, stream>>>(
                bufA, w1, b1, w2, b2, bufA,
                nullptr, nullptr, nullptr, nullptr, N);
        else
            mlp_mfma<true><<<gemm_grid, 256, 0, stream>>>(
                bufA, w1, b1, w2, b2, nullptr,
                ro_w, ro_b, batch, (float*)d_out, N);
    }
}

// Round 8
// 410.862 us; speedup vs baseline: 1.9496x; 1.0277x over previous
//
#include <hip/hip_runtime.h>
#include <hip/hip_fp16.h>

// ---------------------------------------------------------------------------
// GIN forward (eval mode), fp16-MFMA version.
// prep: fold BN into weights, transpose to [n][k] f16.
// CSR build is XCD-range-partitioned: block bid handles edge-chunk bid>>3,
// dst-range bid&7 -> cursor/esrc lines touched by one XCD only (dense
// writebacks, local atomics). esrc stored as u16 (src < 65536).
// per layer: lin_mfma -> aggregate_f16 -> mlp_mfma (fused GEMM1+GEMM2;
// last layer: readout dot + segmented-scan graph reduce).
// ---------------------------------------------------------------------------

#define HD 128
#define NLAYER 3
#define PITCH 136   // f16 units per LDS row (272 B = 17 x 16 B chunks)
#define EPB 2048    // edges per (chunk) block in CSR build

typedef _Float16 half8 __attribute__((ext_vector_type(8)));
typedef float    f32x4 __attribute__((ext_vector_type(4)));

// ---------------- prep: fold BN, convert + transpose weights to f16 --------
__global__ void prep_weights(
    const float* __restrict__ bn_g, const float* __restrict__ bn_b,
    const float* __restrict__ bn_m, const float* __restrict__ bn_v,
    const float* __restrict__ lin_w, const float* __restrict__ lin_b,
    const float* __restrict__ mbn_g, const float* __restrict__ mbn_b,
    const float* __restrict__ mbn_m, const float* __restrict__ mbn_v,
    const float* __restrict__ mlp_w1, const float* __restrict__ mlp_b1,
    const float* __restrict__ mlp_w2,
    _Float16* __restrict__ wtl, float* __restrict__ fbl,
    _Float16* __restrict__ wt1, float* __restrict__ fb1,
    _Float16* __restrict__ wt2)
{
    const int l = blockIdx.x;
    const int t = threadIdx.x;          // 128 threads
    __shared__ float sa[HD], sc[HD], sa2[HD];

    const int lb = l * HD;
    const int wb = l * HD * HD;
    float a  = bn_g[lb + t] * rsqrtf(bn_v[lb + t] + 1e-5f);
    float c  = bn_b[lb + t] - bn_m[lb + t] * a;
    float a2 = mbn_g[lb + t] * rsqrtf(mbn_v[lb + t] + 1e-5f);
    float c2 = mbn_b[lb + t] - mbn_m[lb + t] * a2;
    sa[t] = a; sc[t] = c; sa2[t] = a2;
    __syncthreads();

    float accb = lin_b[lb + t];
    for (int k = 0; k < HD; ++k) accb += sc[k] * lin_w[wb + k * HD + t];
    fbl[lb + t] = accb;
    fb1[lb + t] = a2 * mlp_b1[lb + t] + c2;

    // transposed f16 weights: Wt[j][k]; thread t = k, loop j -> coalesced writes
    for (int j = 0; j < HD; ++j) {
        wtl[wb + j * HD + t] = (_Float16)(sa[t] * lin_w[wb + t * HD + j]);
        wt1[wb + j * HD + t] = (_Float16)(sa2[j] * mlp_w1[wb + t * HD + j]);
        wt2[wb + j * HD + t] = (_Float16)(mlp_w2[wb + t * HD + j]);
    }
}

// ---------------- CSR build (XCD-range partitioned) ----------------
// grid = ceil(e/EPB) * 8; block handles chunk bid>>3, dst-range bid&7.
__global__ void count_deg(const int* __restrict__ dst, int* __restrict__ deg,
                          int e, int npr)
{
    int r = blockIdx.x & 7;
    int chunk = blockIdx.x >> 3;
    int lo = r * npr, hi = lo + npr;
    int base = chunk * EPB;
    int end = base + EPB; if (end > e) end = e;
    for (int i = base + threadIdx.x; i < end; i += 256) {
        int d = dst[i];
        if (d >= lo && d < hi) atomicAdd(&deg[d], 1);
    }
}

__global__ void fill_csr(const int* __restrict__ src, const int* __restrict__ dst,
                         int* __restrict__ cursor,
                         unsigned short* __restrict__ esrc, int e, int npr)
{
    int r = blockIdx.x & 7;
    int chunk = blockIdx.x >> 3;
    int lo = r * npr, hi = lo + npr;
    int base = chunk * EPB;
    int end = base + EPB; if (end > e) end = e;
    for (int i = base + threadIdx.x; i < end; i += 256) {
        int d = dst[i];
        int s = src[i];
        if (d >= lo && d < hi) {
            int p = atomicAdd(&cursor[d], 1);
            esrc[p] = (unsigned short)s;
        }
    }
}

__global__ void scan_blocks(const int* __restrict__ deg, int* __restrict__ excl,
                            int* __restrict__ partials, int n)
{
    __shared__ int wt[4];
    int t = threadIdx.x;
    int base = blockIdx.x * 1024 + t * 4;
    int v0 = (base + 0 < n) ? deg[base + 0] : 0;
    int v1 = (base + 1 < n) ? deg[base + 1] : 0;
    int v2 = (base + 2 < n) ? deg[base + 2] : 0;
    int v3 = (base + 3 < n) ? deg[base + 3] : 0;
    int s = v0 + v1 + v2 + v3;
    int lane = t & 63, w = t >> 6;
    int inc = s;
    #pragma unroll
    for (int d = 1; d < 64; d <<= 1) {
        int o = __shfl_up(inc, d);
        if (lane >= d) inc += o;
    }
    if (lane == 63) wt[w] = inc;
    __syncthreads();
    int off = 0;
    for (int i = 0; i < w; ++i) off += wt[i];
    int ex = off + inc - s;
    if (base + 0 < n) excl[base + 0] = ex; ex += v0;
    if (base + 1 < n) excl[base + 1] = ex; ex += v1;
    if (base + 2 < n) excl[base + 2] = ex; ex += v2;
    if (base + 3 < n) excl[base + 3] = ex;
    if (t == 255) partials[blockIdx.x] = off + inc;
}

__global__ void scan_small(int* __restrict__ partials, int nb)
{
    int t = threadIdx.x;
    int v = (t < nb) ? partials[t] : 0;
    int inc = v;
    #pragma unroll
    for (int d = 1; d < 64; d <<= 1) {
        int o = __shfl_up(inc, d);
        if (t >= d) inc += o;
    }
    if (t < nb) partials[t] = inc - v;
}

__global__ void scan_add(int* __restrict__ rowst, int* __restrict__ cursor,
                         const int* __restrict__ partials, int n, int e)
{
    int idx = blockIdx.x * blockDim.x + threadIdx.x;
    if (idx < n) {
        int v = rowst[idx] + partials[idx >> 10];
        rowst[idx] = v;
        cursor[idx] = v;
    }
    if (idx == 0) rowst[n] = e;
}

// ---------------- lin_mfma: H2 = relu(X @ W + B) -> f16 --------------------
template<bool GATHER>
__global__ __launch_bounds__(256, 3)
void lin_mfma(const float* __restrict__ Xf, const _Float16* __restrict__ Xh,
              const int* __restrict__ xidx,
              const _Float16* __restrict__ Wt, const float* __restrict__ B,
              _Float16* __restrict__ Y, int n)
{
    __shared__ __align__(16) _Float16 sA[64 * PITCH];
    const int t = threadIdx.x;
    const int lane = t & 63;
    const int w = t >> 6;
    const int rw_ = w >> 1, cw = w & 1;
    const int m = lane & 15, g = lane >> 4;
    const int tile = blockIdx.x * 64;

    {
        int row = t >> 2, q = t & 3;
        int gr = tile + row;
        _Float16* dst = &sA[row * PITCH + q * 32];
        if (GATHER) {
            if (gr < n) {
                int id = xidx[gr];
                const float4* src = reinterpret_cast<const float4*>(Xf + (size_t)id * HD) + q * 8;
                #pragma unroll
                for (int c = 0; c < 4; ++c) {
                    float4 va = src[2 * c], vb = src[2 * c + 1];
                    half8 h = {(_Float16)va.x, (_Float16)va.y, (_Float16)va.z, (_Float16)va.w,
                               (_Float16)vb.x, (_Float16)vb.y, (_Float16)vb.z, (_Float16)vb.w};
                    *reinterpret_cast<half8*>(dst + c * 8) = h;
                }
            } else {
                half8 zz = {0, 0, 0, 0, 0, 0, 0, 0};
                #pragma unroll
                for (int c = 0; c < 4; ++c) *reinterpret_cast<half8*>(dst + c * 8) = zz;
            }
        } else {
            half8 zz = {0, 0, 0, 0, 0, 0, 0, 0};
            const half8* src = reinterpret_cast<const half8*>(Xh + (size_t)gr * HD + q * 32);
            #pragma unroll
            for (int c = 0; c < 4; ++c)
                *reinterpret_cast<half8*>(dst + c * 8) = (gr < n) ? src[c] : zz;
        }
    }
    __syncthreads();

    half8 bf[4][4];
    #pragma unroll
    for (int ct4 = 0; ct4 < 4; ++ct4) {
        int ct = 4 * cw + ct4;
        #pragma unroll
        for (int kk = 0; kk < 4; ++kk)
            bf[ct4][kk] = *reinterpret_cast<const half8*>(
                Wt + (size_t)(16 * ct + m) * HD + kk * 32 + g * 8);
    }

    f32x4 acc[2][4];
    #pragma unroll
    for (int i = 0; i < 2; ++i)
        #pragma unroll
        for (int j = 0; j < 4; ++j) acc[i][j] = (f32x4){0.f, 0.f, 0.f, 0.f};

    #pragma unroll
    for (int rg2 = 0; rg2 < 2; ++rg2) {
        int rg = 2 * rw_ + rg2;
        #pragma unroll
        for (int kk = 0; kk < 4; ++kk) {
            half8 a = *reinterpret_cast<const half8*>(
                &sA[(16 * rg + m) * PITCH + kk * 32 + g * 8]);
            #pragma unroll
            for (int ct4 = 0; ct4 < 4; ++ct4)
                acc[rg2][ct4] = __builtin_amdgcn_mfma_f32_16x16x32_f16(
                    a, bf[ct4][kk], acc[rg2][ct4], 0, 0, 0);
        }
    }

    #pragma unroll
    for (int rg2 = 0; rg2 < 2; ++rg2) {
        int rg = 2 * rw_ + rg2;
        #pragma unroll
        for (int ct4 = 0; ct4 < 4; ++ct4) {
            int col = 16 * (4 * cw + ct4) + m;
            float bb = B[col];
            #pragma unroll
            for (int reg = 0; reg < 4; ++reg) {
                int r = tile + 16 * rg + 4 * g + reg;
                if (r < n) {
                    float v = fmaxf(acc[rg2][ct4][reg] + bb, 0.f);
                    Y[(size_t)r * HD + col] = (_Float16)v;
                }
            }
        }
    }
}

// ---------------- aggregate: z = (1+eps)*h2 + sum in-edge h2[src], f16 -----
__global__ void aggregate_f16(const _Float16* __restrict__ h2,
                              const int* __restrict__ rowst,
                              const unsigned short* __restrict__ esrc,
                              const float* __restrict__ epsp,
                              int layer, _Float16* __restrict__ z, int n)
{
    int gw = (blockIdx.x * blockDim.x + threadIdx.x) >> 6;
    int lane = threadIdx.x & 63;
    if (gw >= n) return;
    float se = 1.0f + epsp[layer];
    int rs = __builtin_amdgcn_readfirstlane(rowst[gw]);
    int re = __builtin_amdgcn_readfirstlane(rowst[gw + 1]);
    const half2* hv = reinterpret_cast<const half2*>(h2);
    float2 s = __half22float2(hv[(size_t)gw * 64 + lane]);
    float ax0 = se * s.x, ay0 = se * s.y;
    float ax1 = 0.f, ay1 = 0.f, ax2 = 0.f, ay2 = 0.f, ax3 = 0.f, ay3 = 0.f;
    for (int base = rs; base < re; base += 64) {
        int cnt = re - base; if (cnt > 64) cnt = 64;
        int eid = (base + lane < re) ? (int)esrc[base + lane] : 0;
        int j = 0;
        for (; j + 4 <= cnt; j += 4) {
            int s0 = __shfl(eid, j + 0);
            int s1 = __shfl(eid, j + 1);
            int s2 = __shfl(eid, j + 2);
            int s3 = __shfl(eid, j + 3);
            float2 v0 = __half22float2(hv[(size_t)s0 * 64 + lane]);
            float2 v1 = __half22float2(hv[(size_t)s1 * 64 + lane]);
            float2 v2 = __half22float2(hv[(size_t)s2 * 64 + lane]);
            float2 v3 = __half22float2(hv[(size_t)s3 * 64 + lane]);
            ax0 += v0.x; ay0 += v0.y;
            ax1 += v1.x; ay1 += v1.y;
            ax2 += v2.x; ay2 += v2.y;
            ax3 += v3.x; ay3 += v3.y;
        }
        for (; j < cnt; ++j) {
            int s0 = __shfl(eid, j);
            float2 v0 = __half22float2(hv[(size_t)s0 * 64 + lane]);
            ax0 += v0.x; ay0 += v0.y;
        }
    }
    float ox = (ax0 + ax1) + (ax2 + ax3);
    float oy = (ay0 + ay1) + (ay2 + ay3);
    reinterpret_cast<half2*>(z)[(size_t)gw * 64 + lane] = __floats2half2_rn(ox, oy);
}

// ---------------- mlp_mfma: H = relu(Z@W1+B1)@W2+B2 (fused 2x MFMA GEMM) --
template<bool FUSE_RO>
__global__ __launch_bounds__(256, 3)
void mlp_mfma(const _Float16* __restrict__ Z,
              const _Float16* __restrict__ Wt1, const float* __restrict__ B1,
              const _Float16* __restrict__ Wt2, const float* __restrict__ B2,
              _Float16* __restrict__ H,
              const float* __restrict__ rw, const float* __restrict__ rb,
              const int* __restrict__ batch, float* __restrict__ gout, int n)
{
    __shared__ __align__(16) _Float16 sA[64 * PITCH];
    __shared__ float sD[64][2];
    const int t = threadIdx.x;
    const int lane = t & 63;
    const int w = t >> 6;
    const int rw_ = w >> 1, cw = w & 1;
    const int m = lane & 15, g = lane >> 4;
    const int tile = blockIdx.x * 64;

    {
        int row = t >> 2, q = t & 3;
        int gr = tile + row;
        _Float16* dst = &sA[row * PITCH + q * 32];
        half8 zz = {0, 0, 0, 0, 0, 0, 0, 0};
        const half8* src = reinterpret_cast<const half8*>(Z + (size_t)gr * HD + q * 32);
        #pragma unroll
        for (int c = 0; c < 4; ++c)
            *reinterpret_cast<half8*>(dst + c * 8) = (gr < n) ? src[c] : zz;
    }
    __syncthreads();

    half8 bf[4][4];
    #pragma unroll
    for (int ct4 = 0; ct4 < 4; ++ct4) {
        int ct = 4 * cw + ct4;
        #pragma unroll
        for (int kk = 0; kk < 4; ++kk)
            bf[ct4][kk] = *reinterpret_cast<const half8*>(
                Wt1 + (size_t)(16 * ct + m) * HD + kk * 32 + g * 8);
    }
    f32x4 acc[2][4];
    #pragma unroll
    for (int i = 0; i < 2; ++i)
        #pragma unroll
        for (int j = 0; j < 4; ++j) acc[i][j] = (f32x4){0.f, 0.f, 0.f, 0.f};
    #pragma unroll
    for (int rg2 = 0; rg2 < 2; ++rg2) {
        int rg = 2 * rw_ + rg2;
        #pragma unroll
        for (int kk = 0; kk < 4; ++kk) {
            half8 a = *reinterpret_cast<const half8*>(
                &sA[(16 * rg + m) * PITCH + kk * 32 + g * 8]);
            #pragma unroll
            for (int ct4 = 0; ct4 < 4; ++ct4)
                acc[rg2][ct4] = __builtin_amdgcn_mfma_f32_16x16x32_f16(
                    a, bf[ct4][kk], acc[rg2][ct4], 0, 0, 0);
        }
    }
    __syncthreads();

    #pragma unroll
    for (int rg2 = 0; rg2 < 2; ++rg2) {
        int rg = 2 * rw_ + rg2;
        #pragma unroll
        for (int ct4 = 0; ct4 < 4; ++ct4) {
            int col = 16 * (4 * cw + ct4) + m;
            float bb = B1[col];
            #pragma unroll
            for (int reg = 0; reg < 4; ++reg) {
                int lr = 16 * rg + 4 * g + reg;
                sA[lr * PITCH + col] = (_Float16)fmaxf(acc[rg2][ct4][reg] + bb, 0.f);
            }
        }
    }
    __syncthreads();

    #pragma unroll
    for (int ct4 = 0; ct4 < 4; ++ct4) {
        int ct = 4 * cw + ct4;
        #pragma unroll
        for (int kk = 0; kk < 4; ++kk)
            bf[ct4][kk] = *reinterpret_cast<const half8*>(
                Wt2 + (size_t)(16 * ct + m) * HD + kk * 32 + g * 8);
    }
    f32x4 acc2[2][4];
    #pragma unroll
    for (int i = 0; i < 2; ++i)
        #pragma unroll
        for (int j = 0; j < 4; ++j) acc2[i][j] = (f32x4){0.f, 0.f, 0.f, 0.f};
    #pragma unroll
    for (int rg2 = 0; rg2 < 2; ++rg2) {
        int rg = 2 * rw_ + rg2;
        #pragma unroll
        for (int kk = 0; kk < 4; ++kk) {
            half8 a = *reinterpret_cast<const half8*>(
                &sA[(16 * rg + m) * PITCH + kk * 32 + g * 8]);
            #pragma unroll
            for (int ct4 = 0; ct4 < 4; ++ct4)
                acc2[rg2][ct4] = __builtin_amdgcn_mfma_f32_16x16x32_f16(
                    a, bf[ct4][kk], acc2[rg2][ct4], 0, 0, 0);
        }
    }

    if (!FUSE_RO) {
        #pragma unroll
        for (int rg2 = 0; rg2 < 2; ++rg2) {
            int rg = 2 * rw_ + rg2;
            #pragma unroll
            for (int ct4 = 0; ct4 < 4; ++ct4) {
                int col = 16 * (4 * cw + ct4) + m;
                float bb = B2[col];
                #pragma unroll
                for (int reg = 0; reg < 4; ++reg) {
                    int r = tile + 16 * rg + 4 * g + reg;
                    if (r < n)
                        H[(size_t)r * HD + col] = (_Float16)(acc2[rg2][ct4][reg] + bb);
                }
            }
        }
    } else {
        #pragma unroll
        for (int rg2 = 0; rg2 < 2; ++rg2) {
            int rg = 2 * rw_ + rg2;
            float pr[4] = {0.f, 0.f, 0.f, 0.f};
            #pragma unroll
            for (int ct4 = 0; ct4 < 4; ++ct4) {
                int col = 16 * (4 * cw + ct4) + m;
                float bb = B2[col], rr = rw[col];
                #pragma unroll
                for (int reg = 0; reg < 4; ++reg)
                    pr[reg] = fmaf(acc2[rg2][ct4][reg] + bb, rr, pr[reg]);
            }
            #pragma unroll
            for (int reg = 0; reg < 4; ++reg) {
                #pragma unroll
                for (int d = 1; d < 16; d <<= 1) pr[reg] += __shfl_xor(pr[reg], d);
            }
            if (m == 0) {
                #pragma unroll
                for (int reg = 0; reg < 4; ++reg)
                    sD[16 * rg + 4 * g + reg][cw] = pr[reg];
            }
        }
        __syncthreads();
        if (t < 64) {
            int row = tile + t;
            float v = sD[t][0] + sD[t][1] + rb[0];
            int b = (row < n) ? batch[row] : -1;
            if (row >= n) v = 0.f;
            #pragma unroll
            for (int d = 1; d < 64; d <<= 1) {
                int   ob = __shfl_up(b, d);
                float ov = __shfl_up(v, d);
                if (t >= d && ob == b) v += ov;
            }
            int nb2 = __shfl_down(b, 1);
            bool lastl = (t == 63) || (nb2 != b);
            if (lastl && b >= 0) atomicAdd(&gout[b], v);
        }
    }
}

// ---------------------------------------------------------------------------
extern "C" void kernel_launch(void* const* d_in, const int* in_sizes, int n_in,
                              void* d_out, int out_size, void* d_ws, size_t ws_size,
                              hipStream_t stream)
{
    const int N = in_sizes[0];
    const int E = in_sizes[1] / 2;
    const int G = out_size;

    const int*   x      = (const int*)d_in[0];
    const int*   ei     = (const int*)d_in[1];
    const int*   batch  = (const int*)d_in[2];
    const float* table  = (const float*)d_in[3];
    const float* bn_g   = (const float*)d_in[4];
    const float* bn_b   = (const float*)d_in[5];
    const float* bn_m   = (const float*)d_in[6];
    const float* bn_v   = (const float*)d_in[7];
    const float* lin_w  = (const float*)d_in[8];
    const float* lin_b  = (const float*)d_in[9];
    const float* epsv   = (const float*)d_in[10];
    const float* mlp_w1 = (const float*)d_in[11];
    const float* mlp_b1 = (const float*)d_in[12];
    const float* mbn_g  = (const float*)d_in[13];
    const float* mbn_b  = (const float*)d_in[14];
    const float* mbn_m  = (const float*)d_in[15];
    const float* mbn_v  = (const float*)d_in[16];
    const float* mlp_w2 = (const float*)d_in[17];
    const float* mlp_b2 = (const float*)d_in[18];
    const float* ro_w   = (const float*)d_in[19];
    const float* ro_b   = (const float*)d_in[20];

    const int* esrc_in = ei;
    const int* edst_in = ei + E;

    char* wsp = (char*)d_ws;
    size_t off = 0;
    auto alloc = [&](size_t bytes) {
        void* p = wsp + off;
        off += (bytes + 255) & ~(size_t)255;
        return p;
    };
    _Float16* bufA  = (_Float16*)alloc((size_t)N * HD * 2);  // h / z
    _Float16* bufB  = (_Float16*)alloc((size_t)N * HD * 2);  // h2
    _Float16* wtl   = (_Float16*)alloc((size_t)NLAYER * HD * HD * 2);
    _Float16* wt1   = (_Float16*)alloc((size_t)NLAYER * HD * HD * 2);
    _Float16* wt2   = (_Float16*)alloc((size_t)NLAYER * HD * HD * 2);
    float*    fbl   = (float*)alloc((size_t)NLAYER * HD * 4);
    float*    fb1   = (float*)alloc((size_t)NLAYER * HD * 4);
    int*      deg   = (int*)alloc((size_t)N * 4);
    int*      rowst = (int*)alloc((size_t)(N + 1) * 4);
    int*      cursor= (int*)alloc((size_t)N * 4);
    unsigned short* esrc = (unsigned short*)alloc((size_t)E * 2);
    int*      part  = (int*)alloc(256 * 4);
    (void)ws_size;

    hipMemsetAsync(deg, 0, (size_t)N * 4, stream);
    hipMemsetAsync(d_out, 0, (size_t)G * 4, stream);

    prep_weights<<<NLAYER, HD, 0, stream>>>(
        bn_g, bn_b, bn_m, bn_v, lin_w, lin_b,
        mbn_g, mbn_b, mbn_m, mbn_v, mlp_w1, mlp_b1, mlp_w2,
        wtl, fbl, wt1, fb1, wt2);

    // XCD-range-partitioned CSR build
    const int npr = (N + 7) / 8;                 // nodes per dst-range
    const int chunks = (E + EPB - 1) / EPB;
    count_deg<<<chunks * 8, 256, 0, stream>>>(edst_in, deg, E, npr);
    int nb = (N + 1023) / 1024;
    scan_blocks<<<nb, 256, 0, stream>>>(deg, rowst, part, N);
    scan_small<<<1, 64, 0, stream>>>(part, nb);
    scan_add<<<(N + 255) / 256, 256, 0, stream>>>(rowst, cursor, part, N, E);
    fill_csr<<<chunks * 8, 256, 0, stream>>>(esrc_in, edst_in, cursor, esrc, E, npr);

    const int gemm_grid = (N + 63) / 64;
    const int wave_grid = (N + 3) / 4;

    for (int l = 0; l < NLAYER; ++l) {
        const _Float16* wl = wtl + (size_t)l * HD * HD;
        const float*    bl = fbl + (size_t)l * HD;
        const _Float16* w1 = wt1 + (size_t)l * HD * HD;
        const float*    b1 = fb1 + (size_t)l * HD;
        const _Float16* w2 = wt2 + (size_t)l * HD * HD;
        const float*    b2 = mlp_b2 + (size_t)l * HD;

        if (l == 0)
            lin_mfma<true><<<gemm_grid, 256, 0, stream>>>(
                table, nullptr, x, wl, bl, bufB, N);
        else
            lin_mfma<false><<<gemm_grid, 256, 0, stream>>>(
                nullptr, bufA, nullptr, wl, bl, bufB, N);

        aggregate_f16<<<wave_grid, 256, 0, stream>>>(
            bufB, rowst, esrc, epsv, l, bufA, N);

        if (l < NLAYER - 1)
            mlp_mfma<false><<<gemm_grid, 256, 0, stream>>>(
                bufA, w1, b1, w2, b2, bufA,
                nullptr, nullptr, nullptr, nullptr, N);
        else
            mlp_mfma<true><<<gemm_grid, 256, 0, stream>>>(
                bufA, w1, b1, w2, b2, nullptr,
                ro_w, ro_b, batch, (float*)d_out, N);
    }
}